// Round 2
// baseline (4154.646 us; speedup 1.0000x reference)
//
#include <hip/hip_runtime.h>

// Problem constants (from reference)
#define N_ITEMS     100000
#define EMBED_DIM   64
#define N_REL       3
#define N_EDGES     3200000
#define TOTAL_EDGES (N_REL * N_EDGES)   // 9,600,000 (fits int)

// Bucketing: 32 rows per bucket -> 3125 buckets per relation (exact: 32*3125=100000)
#define LOG_RPB 5
#define RPB     32
#define NB      3125
#define NBK     (N_REL * NB)            // 9375

// ---------------- Phase A1: histogram of edges per (relation,bucket) ----------------
__global__ void hist_kernel(const int* __restrict__ rows, unsigned* __restrict__ ghist) {
    __shared__ unsigned h[NBK];
    for (int j = threadIdx.x; j < NBK; j += blockDim.x) h[j] = 0;
    __syncthreads();
    int stride = gridDim.x * blockDim.x;
    for (int i = blockIdx.x * blockDim.x + threadIdx.x; i < TOTAL_EDGES; i += stride) {
        unsigned r = (unsigned)i / (unsigned)N_EDGES;
        int row = rows[i];
        unsigned b = r * NB + ((unsigned)row >> LOG_RPB);
        atomicAdd(&h[b], 1u);
    }
    __syncthreads();
    for (int j = threadIdx.x; j < NBK; j += blockDim.x)
        if (h[j]) atomicAdd(&ghist[j], h[j]);
}

// ---------------- Phase A2: exclusive scan -> starts & cursors ----------------
__global__ void scan_kernel(const unsigned* __restrict__ ghist,
                            unsigned* __restrict__ starts,
                            unsigned* __restrict__ cursor) {
    __shared__ unsigned part[256];
    const int ITEMS = 37;  // 256*37 = 9472 >= 9375
    int t = threadIdx.x;
    unsigned base = (unsigned)t * ITEMS;
    unsigned sum = 0;
    for (int k = 0; k < ITEMS; k++) {
        unsigned idx = base + k;
        if (idx < NBK) sum += ghist[idx];
    }
    part[t] = sum;
    __syncthreads();
    if (t == 0) {
        unsigned run = 0;
        for (int i = 0; i < 256; i++) { unsigned v = part[i]; part[i] = run; run += v; }
    }
    __syncthreads();
    unsigned run = part[t];
    for (int k = 0; k < ITEMS; k++) {
        unsigned idx = base + k;
        if (idx < NBK) {
            unsigned v = ghist[idx];
            starts[idx] = run;
            cursor[idx] = run;
            run += v;
        }
    }
}

// ---------------- Phase A3: scatter edges into bucket-sorted records ----------------
// record: x = col | (lrow<<17)   (col<2^17, lrow<32)
//         y = bits of val
__global__ void binscatter_kernel(const int* __restrict__ rows,
                                  const int* __restrict__ cols,
                                  const float* __restrict__ vals,
                                  unsigned* __restrict__ cursor,
                                  uint2* __restrict__ recs) {
    int stride = gridDim.x * blockDim.x;
    for (int i = blockIdx.x * blockDim.x + threadIdx.x; i < TOTAL_EDGES; i += stride) {
        unsigned r = (unsigned)i / (unsigned)N_EDGES;
        unsigned row = (unsigned)rows[i];
        unsigned col = (unsigned)cols[i];
        float v = vals[i];
        unsigned b = r * NB + (row >> LOG_RPB);
        unsigned pos = atomicAdd(&cursor[b], 1u);
        uint2 rec;
        rec.x = col | ((row & (RPB - 1)) << 17);
        rec.y = __float_as_uint(v);
        recs[pos] = rec;
    }
}

// ---------------- Phase B: per-bucket LDS accumulation, single coalesced write ----------------
__launch_bounds__(256)
__global__ void gather_kernel(const float* __restrict__ E,
                              const unsigned* __restrict__ starts,
                              const unsigned* __restrict__ counts,
                              const uint2* __restrict__ recs,
                              float* __restrict__ out) {
    __shared__ float accTot[RPB * EMBED_DIM];  // 8 KB
    __shared__ float acc[RPB * EMBED_DIM];     // 8 KB
    __shared__ float deg[RPB];

    int b = blockIdx.x;            // row-bucket 0..NB-1
    int tid = threadIdx.x;
    int g = tid >> 6;              // wave id 0..3 (one edge per wave-iter)
    int d = tid & 63;              // embedding dim

    for (int t = tid; t < RPB * EMBED_DIM; t += 256) accTot[t] = 0.0f;

    for (int r = 0; r < N_REL; r++) {
        for (int t = tid; t < RPB * EMBED_DIM; t += 256) acc[t] = 0.0f;
        if (tid < RPB) deg[tid] = 0.0f;
        __syncthreads();

        unsigned bk = (unsigned)r * NB + b;
        unsigned s = starts[bk];
        int n = (int)counts[bk];

        int j = g;
        for (; j + 4 < n; j += 8) {   // 2-edge unroll per wave for ILP
            uint2 r0 = recs[s + j];
            uint2 r1 = recs[s + j + 4];
            unsigned c0 = r0.x & 0x1FFFFu, l0 = r0.x >> 17;
            unsigned c1 = r1.x & 0x1FFFFu, l1 = r1.x >> 17;
            float w0 = __uint_as_float(r0.y);
            float w1 = __uint_as_float(r1.y);
            float e0 = E[c0 * EMBED_DIM + d];
            float e1 = E[c1 * EMBED_DIM + d];
            atomicAdd(&acc[l0 * EMBED_DIM + d], w0 * e0);
            atomicAdd(&acc[l1 * EMBED_DIM + d], w1 * e1);
            if (d == 0) { atomicAdd(&deg[l0], w0); atomicAdd(&deg[l1], w1); }
        }
        for (; j < n; j += 4) {
            uint2 r0 = recs[s + j];
            unsigned c0 = r0.x & 0x1FFFFu, l0 = r0.x >> 17;
            float w0 = __uint_as_float(r0.y);
            float e0 = E[c0 * EMBED_DIM + d];
            atomicAdd(&acc[l0 * EMBED_DIM + d], w0 * e0);
            if (d == 0) atomicAdd(&deg[l0], w0);
        }
        __syncthreads();
        for (int t = tid; t < RPB * EMBED_DIM; t += 256) {
            float dg = fmaxf(deg[t >> 6], 1.0f);
            accTot[t] += acc[t] / dg;
        }
        __syncthreads();
    }

    // out = E + accTot/3, one coalesced write per row (bucket owns rows exclusively)
    int row0 = b << LOG_RPB;
    for (int t = tid; t < RPB * EMBED_DIM; t += 256) {
        int gidx = row0 * EMBED_DIM + t;
        out[gidx] = E[gidx] + accTot[t] * (1.0f / 3.0f);
    }
}

// ---------------- Fallback path (round-1 kernels) if ws too small ----------------
__global__ void deg_kernel(const int* __restrict__ rows,
                           const float* __restrict__ vals,
                           float* __restrict__ deg) {
    long long i = (long long)blockIdx.x * blockDim.x + threadIdx.x;
    if (i >= TOTAL_EDGES) return;
    int r = (int)(i / N_EDGES);
    int row = rows[i];
    atomicAdd(&deg[(long long)r * N_ITEMS + row], vals[i]);
}

__global__ void inv_kernel(float* __restrict__ deg) {
    int i = blockIdx.x * blockDim.x + threadIdx.x;
    if (i >= N_REL * N_ITEMS) return;
    float d = deg[i];
    d = fmaxf(d, 1.0f);
    deg[i] = 1.0f / (3.0f * d);
}

__global__ void scatter_kernel(const float* __restrict__ E,
                               const int* __restrict__ rows,
                               const int* __restrict__ cols,
                               const float* __restrict__ vals,
                               const float* __restrict__ inv,
                               float* __restrict__ out) {
    long long t = (long long)blockIdx.x * blockDim.x + threadIdx.x;
    long long edge = t >> 6;
    int d = (int)(t & 63);
    if (edge >= TOTAL_EDGES) return;
    int r = (int)(edge / N_EDGES);
    int row = rows[edge];
    int col = cols[edge];
    float w = vals[edge] * inv[r * N_ITEMS + row];
    float msg = w * E[(long long)col * EMBED_DIM + d];
    atomicAdd(&out[(long long)row * EMBED_DIM + d], msg);
}

extern "C" void kernel_launch(void* const* d_in, const int* in_sizes, int n_in,
                              void* d_out, int out_size, void* d_ws, size_t ws_size,
                              hipStream_t stream) {
    const float* E    = (const float*)d_in[0];
    const int*   rows = (const int*)d_in[1];
    const int*   cols = (const int*)d_in[2];
    const float* vals = (const float*)d_in[3];
    float* out = (float*)d_out;

    // Workspace layout (aligned regions)
    const size_t REG = 40960;  // 10240 uints, > NBK*4
    size_t need = 3 * REG + (size_t)TOTAL_EDGES * sizeof(uint2);

    if (ws_size >= need) {
        unsigned* ghist  = (unsigned*)d_ws;
        unsigned* starts = (unsigned*)((char*)d_ws + REG);
        unsigned* cursor = (unsigned*)((char*)d_ws + 2 * REG);
        uint2*    recs   = (uint2*)((char*)d_ws + 3 * REG);

        hipMemsetAsync(ghist, 0, NBK * sizeof(unsigned), stream);
        hist_kernel<<<1536, 256, 0, stream>>>(rows, ghist);
        scan_kernel<<<1, 256, 0, stream>>>(ghist, starts, cursor);
        binscatter_kernel<<<2048, 256, 0, stream>>>(rows, cols, vals, cursor, recs);
        gather_kernel<<<NB, 256, 0, stream>>>(E, starts, ghist, recs, out);
    } else {
        // Fallback: round-1 global-atomic path
        float* deg = (float*)d_ws;  // [3, N_ITEMS]
        hipMemsetAsync(deg, 0, (size_t)N_REL * N_ITEMS * sizeof(float), stream);
        {
            long long total = TOTAL_EDGES;
            int block = 256;
            long long grid = (total + block - 1) / block;
            deg_kernel<<<(unsigned)grid, block, 0, stream>>>(rows, vals, deg);
        }
        {
            int total = N_REL * N_ITEMS;
            int block = 256;
            int grid = (total + block - 1) / block;
            inv_kernel<<<grid, block, 0, stream>>>(deg);
        }
        hipMemcpyAsync(out, E, (size_t)N_ITEMS * EMBED_DIM * sizeof(float),
                       hipMemcpyDeviceToDevice, stream);
        {
            long long threads = (long long)TOTAL_EDGES * 64;
            int block = 256;
            long long grid = (threads + block - 1) / block;
            scatter_kernel<<<(unsigned)grid, block, 0, stream>>>(E, rows, cols, vals, deg, out);
        }
    }
}

// Round 3
// 3947.812 us; speedup vs baseline: 1.0524x; 1.0524x over previous
//
#include <hip/hip_runtime.h>

// Problem constants (from reference)
#define N_ITEMS     100000
#define EMBED_DIM   64
#define N_REL       3
#define N_EDGES     3200000
#define TOTAL_EDGES (N_REL * N_EDGES)   // 9,600,000 (fits int)

// Bucketing: 32 rows per bucket -> 3125 buckets per relation (exact: 32*3125=100000)
#define LOG_RPB 5
#define RPB     32
#define NB      3125
#define NBK     (N_REL * NB)            // 9375

// LDS accumulator row stride: 65 breaks the 8-way bank conflict of stride 64
// (bank = (l + 4q + k) % 32 instead of (4q + k) % 32, which hits only 8 banks)
#define ACC_STRIDE 65

// ---------------- Phase A1: histogram of edges per (relation,bucket) ----------------
__global__ void hist_kernel(const int* __restrict__ rows, unsigned* __restrict__ ghist) {
    __shared__ unsigned h[NBK];
    for (int j = threadIdx.x; j < NBK; j += blockDim.x) h[j] = 0;
    __syncthreads();
    int stride = gridDim.x * blockDim.x;
    for (int i = blockIdx.x * blockDim.x + threadIdx.x; i < TOTAL_EDGES; i += stride) {
        unsigned r = (unsigned)i / (unsigned)N_EDGES;
        int row = rows[i];
        unsigned b = r * NB + ((unsigned)row >> LOG_RPB);
        atomicAdd(&h[b], 1u);
    }
    __syncthreads();
    for (int j = threadIdx.x; j < NBK; j += blockDim.x)
        if (h[j]) atomicAdd(&ghist[j], h[j]);
}

// ---------------- Phase A2: exclusive scan -> starts & cursors ----------------
__global__ void scan_kernel(const unsigned* __restrict__ ghist,
                            unsigned* __restrict__ starts,
                            unsigned* __restrict__ cursor) {
    __shared__ unsigned part[256];
    const int ITEMS = 37;  // 256*37 = 9472 >= 9375
    int t = threadIdx.x;
    unsigned base = (unsigned)t * ITEMS;
    unsigned sum = 0;
    for (int k = 0; k < ITEMS; k++) {
        unsigned idx = base + k;
        if (idx < NBK) sum += ghist[idx];
    }
    part[t] = sum;
    __syncthreads();
    if (t == 0) {
        unsigned run = 0;
        for (int i = 0; i < 256; i++) { unsigned v = part[i]; part[i] = run; run += v; }
    }
    __syncthreads();
    unsigned run = part[t];
    for (int k = 0; k < ITEMS; k++) {
        unsigned idx = base + k;
        if (idx < NBK) {
            unsigned v = ghist[idx];
            starts[idx] = run;
            cursor[idx] = run;
            run += v;
        }
    }
}

// ---------------- Phase A3: scatter edges into bucket-sorted records ----------------
// record: x = col | (lrow<<17)   (col<2^17, lrow<32) ; y = bits of val
__global__ void binscatter_kernel(const int* __restrict__ rows,
                                  const int* __restrict__ cols,
                                  const float* __restrict__ vals,
                                  unsigned* __restrict__ cursor,
                                  uint2* __restrict__ recs) {
    int stride = gridDim.x * blockDim.x;
    for (int i = blockIdx.x * blockDim.x + threadIdx.x; i < TOTAL_EDGES; i += stride) {
        unsigned r = (unsigned)i / (unsigned)N_EDGES;
        unsigned row = (unsigned)rows[i];
        unsigned col = (unsigned)cols[i];
        float v = vals[i];
        unsigned b = r * NB + (row >> LOG_RPB);
        unsigned pos = atomicAdd(&cursor[b], 1u);
        uint2 rec;
        rec.x = col | ((row & (RPB - 1)) << 17);
        rec.y = __float_as_uint(v);
        recs[pos] = rec;
    }
}

// ---------------- Phase B: per-(relation,bucket) LDS accumulation ----------------
// One block per (r, bucket). Wave handles 4 edges/iteration (16 lanes x float4 each),
// unrolled x4 -> 16 edges (4 b64 + 4 dwordx4 loads) in flight per wave.
// Partial (acc / (3*deg)) is atomically added to out (pre-filled with E).
__launch_bounds__(256)
__global__ void gather_kernel(const float4* __restrict__ E4,
                              const unsigned* __restrict__ starts,
                              const unsigned* __restrict__ counts,
                              const uint2* __restrict__ recs,
                              float* __restrict__ out) {
    __shared__ float acc[RPB * ACC_STRIDE];  // 8.32 KB
    __shared__ float deg[RPB];

    int bk = blockIdx.x;           // r*NB + b
    int tid = threadIdx.x;
    int w = tid >> 6;              // wave 0..3
    int lane = tid & 63;
    int sub = lane >> 4;           // edge slot 0..3 within the wave
    int q = lane & 15;             // dim quad (q*4 .. q*4+3)

    for (int t = tid; t < RPB * ACC_STRIDE; t += 256) acc[t] = 0.0f;
    if (tid < RPB) deg[tid] = 0.0f;
    __syncthreads();

    unsigned s = starts[bk];
    int n = (int)counts[bk];

    const int STEP = 16;           // 4 waves x 4 edge slots
    int i = w * 4 + sub;

    for (; i + 3 * STEP < n; i += 4 * STEP) {
        uint2 r0 = recs[s + i];
        uint2 r1 = recs[s + i + STEP];
        uint2 r2 = recs[s + i + 2 * STEP];
        uint2 r3 = recs[s + i + 3 * STEP];
        float4 e0 = E4[(r0.x & 0x1FFFFu) * 16 + q];
        float4 e1 = E4[(r1.x & 0x1FFFFu) * 16 + q];
        float4 e2 = E4[(r2.x & 0x1FFFFu) * 16 + q];
        float4 e3 = E4[(r3.x & 0x1FFFFu) * 16 + q];
        float w0 = __uint_as_float(r0.y); int l0 = (int)(r0.x >> 17);
        float w1 = __uint_as_float(r1.y); int l1 = (int)(r1.x >> 17);
        float w2 = __uint_as_float(r2.y); int l2 = (int)(r2.x >> 17);
        float w3 = __uint_as_float(r3.y); int l3 = (int)(r3.x >> 17);
        int b0 = l0 * ACC_STRIDE + q * 4;
        int b1 = l1 * ACC_STRIDE + q * 4;
        int b2 = l2 * ACC_STRIDE + q * 4;
        int b3 = l3 * ACC_STRIDE + q * 4;
        atomicAdd(&acc[b0 + 0], w0 * e0.x); atomicAdd(&acc[b0 + 1], w0 * e0.y);
        atomicAdd(&acc[b0 + 2], w0 * e0.z); atomicAdd(&acc[b0 + 3], w0 * e0.w);
        atomicAdd(&acc[b1 + 0], w1 * e1.x); atomicAdd(&acc[b1 + 1], w1 * e1.y);
        atomicAdd(&acc[b1 + 2], w1 * e1.z); atomicAdd(&acc[b1 + 3], w1 * e1.w);
        atomicAdd(&acc[b2 + 0], w2 * e2.x); atomicAdd(&acc[b2 + 1], w2 * e2.y);
        atomicAdd(&acc[b2 + 2], w2 * e2.z); atomicAdd(&acc[b2 + 3], w2 * e2.w);
        atomicAdd(&acc[b3 + 0], w3 * e3.x); atomicAdd(&acc[b3 + 1], w3 * e3.y);
        atomicAdd(&acc[b3 + 2], w3 * e3.z); atomicAdd(&acc[b3 + 3], w3 * e3.w);
        if (q == 0) {
            atomicAdd(&deg[l0], w0); atomicAdd(&deg[l1], w1);
            atomicAdd(&deg[l2], w2); atomicAdd(&deg[l3], w3);
        }
    }
    for (; i < n; i += STEP) {
        uint2 r0 = recs[s + i];
        float4 e0 = E4[(r0.x & 0x1FFFFu) * 16 + q];
        float w0 = __uint_as_float(r0.y); int l0 = (int)(r0.x >> 17);
        int b0 = l0 * ACC_STRIDE + q * 4;
        atomicAdd(&acc[b0 + 0], w0 * e0.x); atomicAdd(&acc[b0 + 1], w0 * e0.y);
        atomicAdd(&acc[b0 + 2], w0 * e0.z); atomicAdd(&acc[b0 + 3], w0 * e0.w);
        if (q == 0) atomicAdd(&deg[l0], w0);
    }
    __syncthreads();

    int b = bk % NB;
    int row0 = b << LOG_RPB;
    for (int t = tid; t < RPB * EMBED_DIM; t += 256) {
        int l = t >> 6, c = t & 63;
        float dg = fmaxf(deg[l], 1.0f);
        atomicAdd(&out[row0 * EMBED_DIM + t], acc[l * ACC_STRIDE + c] / (3.0f * dg));
    }
}

// ---------------- Fallback path (round-1 kernels) if ws too small ----------------
__global__ void deg_kernel(const int* __restrict__ rows,
                           const float* __restrict__ vals,
                           float* __restrict__ deg) {
    long long i = (long long)blockIdx.x * blockDim.x + threadIdx.x;
    if (i >= TOTAL_EDGES) return;
    int r = (int)(i / N_EDGES);
    int row = rows[i];
    atomicAdd(&deg[(long long)r * N_ITEMS + row], vals[i]);
}

__global__ void inv_kernel(float* __restrict__ deg) {
    int i = blockIdx.x * blockDim.x + threadIdx.x;
    if (i >= N_REL * N_ITEMS) return;
    float d = deg[i];
    d = fmaxf(d, 1.0f);
    deg[i] = 1.0f / (3.0f * d);
}

__global__ void scatter_kernel(const float* __restrict__ E,
                               const int* __restrict__ rows,
                               const int* __restrict__ cols,
                               const float* __restrict__ vals,
                               const float* __restrict__ inv,
                               float* __restrict__ out) {
    long long t = (long long)blockIdx.x * blockDim.x + threadIdx.x;
    long long edge = t >> 6;
    int d = (int)(t & 63);
    if (edge >= TOTAL_EDGES) return;
    int r = (int)(edge / N_EDGES);
    int row = rows[edge];
    int col = cols[edge];
    float w = vals[edge] * inv[r * N_ITEMS + row];
    float msg = w * E[(long long)col * EMBED_DIM + d];
    atomicAdd(&out[(long long)row * EMBED_DIM + d], msg);
}

extern "C" void kernel_launch(void* const* d_in, const int* in_sizes, int n_in,
                              void* d_out, int out_size, void* d_ws, size_t ws_size,
                              hipStream_t stream) {
    const float* E    = (const float*)d_in[0];
    const int*   rows = (const int*)d_in[1];
    const int*   cols = (const int*)d_in[2];
    const float* vals = (const float*)d_in[3];
    float* out = (float*)d_out;

    const size_t REG = 40960;  // 10240 uints, > NBK*4
    size_t need = 3 * REG + (size_t)TOTAL_EDGES * sizeof(uint2);

    if (ws_size >= need) {
        unsigned* ghist  = (unsigned*)d_ws;
        unsigned* starts = (unsigned*)((char*)d_ws + REG);
        unsigned* cursor = (unsigned*)((char*)d_ws + 2 * REG);
        uint2*    recs   = (uint2*)((char*)d_ws + 3 * REG);

        hipMemsetAsync(ghist, 0, NBK * sizeof(unsigned), stream);
        // residual: out = E (atomic partials add on top)
        hipMemcpyAsync(out, E, (size_t)N_ITEMS * EMBED_DIM * sizeof(float),
                       hipMemcpyDeviceToDevice, stream);
        hist_kernel<<<1536, 256, 0, stream>>>(rows, ghist);
        scan_kernel<<<1, 256, 0, stream>>>(ghist, starts, cursor);
        binscatter_kernel<<<2048, 256, 0, stream>>>(rows, cols, vals, cursor, recs);
        gather_kernel<<<NBK, 256, 0, stream>>>((const float4*)E, starts, ghist, recs, out);
    } else {
        // Fallback: round-1 global-atomic path
        float* deg = (float*)d_ws;  // [3, N_ITEMS]
        hipMemsetAsync(deg, 0, (size_t)N_REL * N_ITEMS * sizeof(float), stream);
        {
            long long total = TOTAL_EDGES;
            int block = 256;
            long long grid = (total + block - 1) / block;
            deg_kernel<<<(unsigned)grid, block, 0, stream>>>(rows, vals, deg);
        }
        {
            int total = N_REL * N_ITEMS;
            int block = 256;
            int grid = (total + block - 1) / block;
            inv_kernel<<<grid, block, 0, stream>>>(deg);
        }
        hipMemcpyAsync(out, E, (size_t)N_ITEMS * EMBED_DIM * sizeof(float),
                       hipMemcpyDeviceToDevice, stream);
        {
            long long threads = (long long)TOTAL_EDGES * 64;
            int block = 256;
            long long grid = (threads + block - 1) / block;
            scatter_kernel<<<(unsigned)grid, block, 0, stream>>>(E, rows, cols, vals, deg, out);
        }
    }
}

// Round 4
// 2243.495 us; speedup vs baseline: 1.8519x; 1.7597x over previous
//
#include <hip/hip_runtime.h>

// Problem constants (from reference)
#define N_ITEMS     100000
#define EMBED_DIM   64
#define N_REL       3
#define N_EDGES     3200000
#define TOTAL_EDGES (N_REL * N_EDGES)   // 9,600,000 (fits int)
#define NKEY        (N_REL * N_ITEMS)   // 300,000 fine-grained (rel,row) segments

// ---------------- Phase A1: per-(rel,row) edge counts (global atomics) ----------------
__global__ void hist300_kernel(const int* __restrict__ rows, unsigned* __restrict__ cnt) {
    int stride = gridDim.x * blockDim.x;
    for (int i = blockIdx.x * blockDim.x + threadIdx.x; i < TOTAL_EDGES; i += stride) {
        unsigned r = (unsigned)i / (unsigned)N_EDGES;
        unsigned key = r * N_ITEMS + (unsigned)rows[i];
        atomicAdd(&cnt[key], 1u);
    }
}

// ---------------- Phase A2: exclusive scan over 300k counts ----------------
// cnt (in: counts) becomes the mutable cursor; starts[NKEY+1] gets the clean bounds.
__global__ void scan300_kernel(unsigned* __restrict__ cnt,
                               unsigned* __restrict__ starts) {
    __shared__ unsigned part[1024];
    const int ITEMS = 293;  // 1024*293 = 300,032 >= NKEY
    int t = threadIdx.x;
    unsigned base = (unsigned)t * ITEMS;
    unsigned sum = 0;
    for (int k = 0; k < ITEMS; k++) {
        unsigned idx = base + k;
        if (idx < NKEY) sum += cnt[idx];
    }
    part[t] = sum;
    __syncthreads();
    if (t == 0) {
        unsigned run = 0;
        for (int i = 0; i < 1024; i++) { unsigned v = part[i]; part[i] = run; run += v; }
    }
    __syncthreads();
    unsigned run = part[t];
    for (int k = 0; k < ITEMS; k++) {
        unsigned idx = base + k;
        if (idx < NKEY) {
            unsigned v = cnt[idx];
            starts[idx] = run;
            cnt[idx] = run;   // cursor for binscatter
            run += v;
        }
    }
    if (t == 1023) starts[NKEY] = run;  // total
}

// ---------------- Phase A3: scatter edges into CSR order ----------------
// record: x = col, y = bits of val (row implicit in segment)
__global__ void binscatter2_kernel(const int* __restrict__ rows,
                                   const int* __restrict__ cols,
                                   const float* __restrict__ vals,
                                   unsigned* __restrict__ cursor,
                                   uint2* __restrict__ recs) {
    int stride = gridDim.x * blockDim.x;
    for (int i = blockIdx.x * blockDim.x + threadIdx.x; i < TOTAL_EDGES; i += stride) {
        unsigned r = (unsigned)i / (unsigned)N_EDGES;
        unsigned key = r * N_ITEMS + (unsigned)rows[i];
        unsigned pos = atomicAdd(&cursor[key], 1u);
        uint2 rec;
        rec.x = (unsigned)cols[i];
        rec.y = __float_as_uint(vals[i]);
        recs[pos] = rec;
    }
}

// ---------------- Phase B: atomic-free CSR gather ----------------
// One block (192 thr = 3 waves) per row. Wave w = relation w, lane = dim.
// Register-only accumulation; val is wave-uniform so every lane carries deg.
__launch_bounds__(192)
__global__ void gather_csr_kernel(const float* __restrict__ E,
                                  const unsigned* __restrict__ starts,
                                  const uint2* __restrict__ recs,
                                  float* __restrict__ out) {
    __shared__ float part[N_REL * EMBED_DIM];   // 768 B
    int row = blockIdx.x;
    int w = threadIdx.x >> 6;      // relation 0..2
    int d = threadIdx.x & 63;      // embedding dim

    unsigned key = (unsigned)w * N_ITEMS + (unsigned)row;
    unsigned s = starts[key];
    int n = (int)(starts[key + 1] - s);
    const uint2* __restrict__ p = recs + s;

    float acc = 0.0f, deg = 0.0f;
    int j = 0;
    for (; j + 8 <= n; j += 8) {
        uint2 a[8];
        #pragma unroll
        for (int k = 0; k < 8; k++) a[k] = p[j + k];
        float e[8];
        #pragma unroll
        for (int k = 0; k < 8; k++) e[k] = E[a[k].x * EMBED_DIM + d];
        #pragma unroll
        for (int k = 0; k < 8; k++) {
            float wv = __uint_as_float(a[k].y);
            acc += wv * e[k];
            deg += wv;
        }
    }
    for (; j < n; j++) {
        uint2 a = p[j];
        float wv = __uint_as_float(a.y);
        acc += wv * E[a.x * EMBED_DIM + d];
        deg += wv;
    }

    part[w * EMBED_DIM + d] = acc / (3.0f * fmaxf(deg, 1.0f));
    __syncthreads();
    if (threadIdx.x < EMBED_DIM) {
        int gi = row * EMBED_DIM + threadIdx.x;
        out[gi] = E[gi] + part[threadIdx.x]
                        + part[EMBED_DIM + threadIdx.x]
                        + part[2 * EMBED_DIM + threadIdx.x];
    }
}

// ---------------- Fallback path (round-1 kernels) if ws too small ----------------
__global__ void deg_kernel(const int* __restrict__ rows,
                           const float* __restrict__ vals,
                           float* __restrict__ deg) {
    long long i = (long long)blockIdx.x * blockDim.x + threadIdx.x;
    if (i >= TOTAL_EDGES) return;
    int r = (int)(i / N_EDGES);
    int row = rows[i];
    atomicAdd(&deg[(long long)r * N_ITEMS + row], vals[i]);
}

__global__ void inv_kernel(float* __restrict__ deg) {
    int i = blockIdx.x * blockDim.x + threadIdx.x;
    if (i >= N_REL * N_ITEMS) return;
    float d = deg[i];
    d = fmaxf(d, 1.0f);
    deg[i] = 1.0f / (3.0f * d);
}

__global__ void scatter_kernel(const float* __restrict__ E,
                               const int* __restrict__ rows,
                               const int* __restrict__ cols,
                               const float* __restrict__ vals,
                               const float* __restrict__ inv,
                               float* __restrict__ out) {
    long long t = (long long)blockIdx.x * blockDim.x + threadIdx.x;
    long long edge = t >> 6;
    int d = (int)(t & 63);
    if (edge >= TOTAL_EDGES) return;
    int r = (int)(edge / N_EDGES);
    int row = rows[edge];
    int col = cols[edge];
    float w = vals[edge] * inv[r * N_ITEMS + row];
    float msg = w * E[(long long)col * EMBED_DIM + d];
    atomicAdd(&out[(long long)row * EMBED_DIM + d], msg);
}

extern "C" void kernel_launch(void* const* d_in, const int* in_sizes, int n_in,
                              void* d_out, int out_size, void* d_ws, size_t ws_size,
                              hipStream_t stream) {
    const float* E    = (const float*)d_in[0];
    const int*   rows = (const int*)d_in[1];
    const int*   cols = (const int*)d_in[2];
    const float* vals = (const float*)d_in[3];
    float* out = (float*)d_out;

    // Workspace layout: starts[NKEY+1] | cursor[NKEY] | recs[TOTAL_EDGES]
    const size_t REGA = 1204224;  // >= (NKEY+1)*4, 4 KB aligned
    size_t need = 2 * REGA + (size_t)TOTAL_EDGES * sizeof(uint2);

    if (ws_size >= need) {
        unsigned* starts = (unsigned*)d_ws;
        unsigned* cursor = (unsigned*)((char*)d_ws + REGA);
        uint2*    recs   = (uint2*)((char*)d_ws + 2 * REGA);

        hipMemsetAsync(cursor, 0, NKEY * sizeof(unsigned), stream);
        hist300_kernel<<<1536, 256, 0, stream>>>(rows, cursor);
        scan300_kernel<<<1, 1024, 0, stream>>>(cursor, starts);
        binscatter2_kernel<<<2048, 256, 0, stream>>>(rows, cols, vals, cursor, recs);
        gather_csr_kernel<<<N_ITEMS, 192, 0, stream>>>(E, starts, recs, out);
    } else {
        // Fallback: round-1 global-atomic path (needs only 1.2 MB ws)
        float* deg = (float*)d_ws;  // [3, N_ITEMS]
        hipMemsetAsync(deg, 0, (size_t)N_REL * N_ITEMS * sizeof(float), stream);
        {
            long long total = TOTAL_EDGES;
            int block = 256;
            long long grid = (total + block - 1) / block;
            deg_kernel<<<(unsigned)grid, block, 0, stream>>>(rows, vals, deg);
        }
        {
            int total = N_REL * N_ITEMS;
            int block = 256;
            int grid = (total + block - 1) / block;
            inv_kernel<<<grid, block, 0, stream>>>(deg);
        }
        hipMemcpyAsync(out, E, (size_t)N_ITEMS * EMBED_DIM * sizeof(float),
                       hipMemcpyDeviceToDevice, stream);
        {
            long long threads = (long long)TOTAL_EDGES * 64;
            int block = 256;
            long long grid = (threads + block - 1) / block;
            scatter_kernel<<<(unsigned)grid, block, 0, stream>>>(E, rows, cols, vals, deg, out);
        }
    }
}

// Round 5
// 1340.335 us; speedup vs baseline: 3.0997x; 1.6738x over previous
//
#include <hip/hip_runtime.h>

// Problem constants (from reference)
#define N_ITEMS     100000
#define EMBED_DIM   64
#define N_REL       3
#define N_EDGES     3200000
#define TOTAL_EDGES (N_REL * N_EDGES)   // 9,600,000 (fits int)
#define NKEY        (N_REL * N_ITEMS)   // 300,000 fine-grained (rel,row) segments
#define NBS         ((NKEY + 255) / 256)  // 1172 scan blocks

// ---------------- Phase A1: per-(rel,row) edge counts (global atomics) ----------------
__global__ void hist300_kernel(const int* __restrict__ rows, unsigned* __restrict__ cnt) {
    int stride = gridDim.x * blockDim.x;
    for (int i = blockIdx.x * blockDim.x + threadIdx.x; i < TOTAL_EDGES; i += stride) {
        unsigned r = (unsigned)i / (unsigned)N_EDGES;
        unsigned key = r * N_ITEMS + (unsigned)rows[i];
        atomicAdd(&cnt[key], 1u);
    }
}

// ---------------- Phase A2a: per-block sums of counts ----------------
__global__ void scan_blocksum(const unsigned* __restrict__ cnt, unsigned* __restrict__ bsum) {
    __shared__ unsigned s[256];
    int i = blockIdx.x * 256 + threadIdx.x;
    s[threadIdx.x] = (i < NKEY) ? cnt[i] : 0u;
    __syncthreads();
    for (int off = 128; off > 0; off >>= 1) {
        if (threadIdx.x < off) s[threadIdx.x] += s[threadIdx.x + off];
        __syncthreads();
    }
    if (threadIdx.x == 0) bsum[blockIdx.x] = s[0];
}

// ---------------- Phase A2b: exclusive scan of the 1172 block sums (in place) ----------------
__global__ void scan_partials(unsigned* __restrict__ bsum, unsigned* __restrict__ starts) {
    const int IT = 5;  // 256*5 = 1280 >= NBS
    int t = threadIdx.x;
    unsigned loc[IT];
    unsigned sum = 0;
    #pragma unroll
    for (int k = 0; k < IT; k++) {
        int idx = t * IT + k;
        loc[k] = (idx < NBS) ? bsum[idx] : 0u;
        sum += loc[k];
    }
    int lane = t & 63, wid = t >> 6;
    unsigned inc = sum;
    #pragma unroll
    for (int d = 1; d < 64; d <<= 1) {
        unsigned x = __shfl_up(inc, d, 64);
        if (lane >= d) inc += x;
    }
    __shared__ unsigned woff[4], woffEx[4];
    if (lane == 63) woff[wid] = inc;
    __syncthreads();
    if (t == 0) { unsigned run = 0; for (int k = 0; k < 4; k++) { woffEx[k] = run; run += woff[k]; } }
    __syncthreads();
    unsigned ex = inc - sum + woffEx[wid];
    #pragma unroll
    for (int k = 0; k < IT; k++) {
        int idx = t * IT + k;
        if (idx < NBS) { bsum[idx] = ex; ex += loc[k]; }
    }
    if (t == 0) starts[NKEY] = (unsigned)TOTAL_EDGES;
}

// ---------------- Phase A2c: per-block exclusive scan + offset -> starts & cursor ----------------
// key_arr is read (counts) and overwritten (starts); each thread reads its own
// element before writing it, so in-place aliasing is safe.
__global__ void scan_final(unsigned* key_arr,
                           const unsigned* __restrict__ bsum,
                           unsigned* __restrict__ cursor) {
    int i = blockIdx.x * 256 + threadIdx.x;
    unsigned v = (i < NKEY) ? key_arr[i] : 0u;
    int lane = threadIdx.x & 63, wid = threadIdx.x >> 6;
    unsigned inc = v;
    #pragma unroll
    for (int d = 1; d < 64; d <<= 1) {
        unsigned x = __shfl_up(inc, d, 64);
        if (lane >= d) inc += x;
    }
    __shared__ unsigned woff[4], woffEx[4];
    if (lane == 63) woff[wid] = inc;
    __syncthreads();
    if (threadIdx.x == 0) { unsigned run = 0; for (int k = 0; k < 4; k++) { woffEx[k] = run; run += woff[k]; } }
    __syncthreads();
    unsigned ex = inc - v + woffEx[wid] + bsum[blockIdx.x];
    if (i < NKEY) { key_arr[i] = ex; cursor[i] = ex; }
}

// ---------------- Phase A3: scatter edges into CSR order ----------------
// record: x = col, y = bits of val (row implicit in segment)
__global__ void binscatter2_kernel(const int* __restrict__ rows,
                                   const int* __restrict__ cols,
                                   const float* __restrict__ vals,
                                   unsigned* __restrict__ cursor,
                                   uint2* __restrict__ recs) {
    int stride = gridDim.x * blockDim.x;
    for (int i = blockIdx.x * blockDim.x + threadIdx.x; i < TOTAL_EDGES; i += stride) {
        unsigned r = (unsigned)i / (unsigned)N_EDGES;
        unsigned key = r * N_ITEMS + (unsigned)rows[i];
        unsigned pos = atomicAdd(&cursor[key], 1u);
        uint2 rec;
        rec.x = (unsigned)cols[i];
        rec.y = __float_as_uint(vals[i]);
        recs[pos] = rec;
    }
}

// ---------------- Phase B: atomic-free CSR gather ----------------
// One block (192 thr = 3 waves) per row. Wave w = relation w, lane = dim.
// Register-only accumulation; val is wave-uniform so every lane carries deg.
__launch_bounds__(192)
__global__ void gather_csr_kernel(const float* __restrict__ E,
                                  const unsigned* __restrict__ starts,
                                  const uint2* __restrict__ recs,
                                  float* __restrict__ out) {
    __shared__ float part[N_REL * EMBED_DIM];   // 768 B
    int row = blockIdx.x;
    int w = threadIdx.x >> 6;      // relation 0..2
    int d = threadIdx.x & 63;      // embedding dim

    unsigned key = (unsigned)w * N_ITEMS + (unsigned)row;
    unsigned s = starts[key];
    int n = (int)(starts[key + 1] - s);
    const uint2* __restrict__ p = recs + s;

    float acc = 0.0f, deg = 0.0f;
    int j = 0;
    for (; j + 8 <= n; j += 8) {
        uint2 a[8];
        #pragma unroll
        for (int k = 0; k < 8; k++) a[k] = p[j + k];
        float e[8];
        #pragma unroll
        for (int k = 0; k < 8; k++) e[k] = E[a[k].x * EMBED_DIM + d];
        #pragma unroll
        for (int k = 0; k < 8; k++) {
            float wv = __uint_as_float(a[k].y);
            acc += wv * e[k];
            deg += wv;
        }
    }
    for (; j < n; j++) {
        uint2 a = p[j];
        float wv = __uint_as_float(a.y);
        acc += wv * E[a.x * EMBED_DIM + d];
        deg += wv;
    }

    part[w * EMBED_DIM + d] = acc / (3.0f * fmaxf(deg, 1.0f));
    __syncthreads();
    if (threadIdx.x < EMBED_DIM) {
        int gi = row * EMBED_DIM + threadIdx.x;
        out[gi] = E[gi] + part[threadIdx.x]
                        + part[EMBED_DIM + threadIdx.x]
                        + part[2 * EMBED_DIM + threadIdx.x];
    }
}

// ---------------- Fallback path (round-1 kernels) if ws too small ----------------
__global__ void deg_kernel(const int* __restrict__ rows,
                           const float* __restrict__ vals,
                           float* __restrict__ deg) {
    long long i = (long long)blockIdx.x * blockDim.x + threadIdx.x;
    if (i >= TOTAL_EDGES) return;
    int r = (int)(i / N_EDGES);
    int row = rows[i];
    atomicAdd(&deg[(long long)r * N_ITEMS + row], vals[i]);
}

__global__ void inv_kernel(float* __restrict__ deg) {
    int i = blockIdx.x * blockDim.x + threadIdx.x;
    if (i >= N_REL * N_ITEMS) return;
    float d = deg[i];
    d = fmaxf(d, 1.0f);
    deg[i] = 1.0f / (3.0f * d);
}

__global__ void scatter_kernel(const float* __restrict__ E,
                               const int* __restrict__ rows,
                               const int* __restrict__ cols,
                               const float* __restrict__ vals,
                               const float* __restrict__ inv,
                               float* __restrict__ out) {
    long long t = (long long)blockIdx.x * blockDim.x + threadIdx.x;
    long long edge = t >> 6;
    int d = (int)(t & 63);
    if (edge >= TOTAL_EDGES) return;
    int r = (int)(edge / N_EDGES);
    int row = rows[edge];
    int col = cols[edge];
    float w = vals[edge] * inv[r * N_ITEMS + row];
    float msg = w * E[(long long)col * EMBED_DIM + d];
    atomicAdd(&out[(long long)row * EMBED_DIM + d], msg);
}

extern "C" void kernel_launch(void* const* d_in, const int* in_sizes, int n_in,
                              void* d_out, int out_size, void* d_ws, size_t ws_size,
                              hipStream_t stream) {
    const float* E    = (const float*)d_in[0];
    const int*   rows = (const int*)d_in[1];
    const int*   cols = (const int*)d_in[2];
    const float* vals = (const float*)d_in[3];
    float* out = (float*)d_out;

    // Workspace layout: A = cnt/starts[NKEY+1] | B = cursor[NKEY] | C = bsum[NBS] | D = recs
    const size_t REGA = 1204224;  // >= (NKEY+1)*4, 4 KB aligned
    const size_t REGC = 8192;     // >= NBS*4
    size_t need = 2 * REGA + REGC + (size_t)TOTAL_EDGES * sizeof(uint2);

    if (ws_size >= need) {
        unsigned* keyA   = (unsigned*)d_ws;                          // counts -> starts
        unsigned* cursor = (unsigned*)((char*)d_ws + REGA);
        unsigned* bsum   = (unsigned*)((char*)d_ws + 2 * REGA);
        uint2*    recs   = (uint2*)((char*)d_ws + 2 * REGA + REGC);

        hipMemsetAsync(keyA, 0, NKEY * sizeof(unsigned), stream);
        hist300_kernel<<<1536, 256, 0, stream>>>(rows, keyA);
        scan_blocksum<<<NBS, 256, 0, stream>>>(keyA, bsum);
        scan_partials<<<1, 256, 0, stream>>>(bsum, keyA);
        scan_final<<<NBS, 256, 0, stream>>>(keyA, bsum, cursor);
        binscatter2_kernel<<<2048, 256, 0, stream>>>(rows, cols, vals, cursor, recs);
        gather_csr_kernel<<<N_ITEMS, 192, 0, stream>>>(E, keyA, recs, out);
    } else {
        // Fallback: round-1 global-atomic path (needs only 1.2 MB ws)
        float* deg = (float*)d_ws;  // [3, N_ITEMS]
        hipMemsetAsync(deg, 0, (size_t)N_REL * N_ITEMS * sizeof(float), stream);
        {
            long long total = TOTAL_EDGES;
            int block = 256;
            long long grid = (total + block - 1) / block;
            deg_kernel<<<(unsigned)grid, block, 0, stream>>>(rows, vals, deg);
        }
        {
            int total = N_REL * N_ITEMS;
            int block = 256;
            int grid = (total + block - 1) / block;
            inv_kernel<<<grid, block, 0, stream>>>(deg);
        }
        hipMemcpyAsync(out, E, (size_t)N_ITEMS * EMBED_DIM * sizeof(float),
                       hipMemcpyDeviceToDevice, stream);
        {
            long long threads = (long long)TOTAL_EDGES * 64;
            int block = 256;
            long long grid = (threads + block - 1) / block;
            scatter_kernel<<<(unsigned)grid, block, 0, stream>>>(E, rows, cols, vals, deg, out);
        }
    }
}

// Round 6
// 785.535 us; speedup vs baseline: 5.2889x; 1.7063x over previous
//
#include <hip/hip_runtime.h>

// Problem constants (from reference)
#define N_ITEMS     100000
#define EMBED_DIM   64
#define N_REL       3
#define N_EDGES     3200000
#define TOTAL_EDGES (N_REL * N_EDGES)   // 9,600,000 (fits int)
#define NKEY        (N_REL * N_ITEMS)   // 300,000 exact (rel,row) segments

// Coarse buckets: 1024 rows each -> 98 per relation, 294 total
#define LOG_CB   10
#define CB_ROWS  1024
#define NCB      98
#define NCB_TOT  (N_REL * NCB)          // 294
#define TILE     4096                   // edges staged per partition block

// ============================ v6 pipeline ============================

// ---- P1: global histogram over 294 coarse buckets (LDS-privatized) ----
__global__ void hist294_kernel(const int* __restrict__ rows, unsigned* __restrict__ gcnt) {
    __shared__ unsigned h[NCB_TOT];
    for (int j = threadIdx.x; j < NCB_TOT; j += 256) h[j] = 0;
    __syncthreads();
    int stride = gridDim.x * blockDim.x;
    for (int i = blockIdx.x * blockDim.x + threadIdx.x; i < TOTAL_EDGES; i += stride) {
        unsigned r = (unsigned)i / (unsigned)N_EDGES;
        unsigned cb = r * NCB + ((unsigned)rows[i] >> LOG_CB);
        atomicAdd(&h[cb], 1u);
    }
    __syncthreads();
    for (int j = threadIdx.x; j < NCB_TOT; j += 256)
        if (h[j]) atomicAdd(&gcnt[j], h[j]);
}

// ---- P2: scan 294 counts -> gstart[295], gcursor[294]; seed startsKey[NKEY] ----
__global__ void scan294_kernel(const unsigned* __restrict__ gcnt,
                               unsigned* __restrict__ gstart,
                               unsigned* __restrict__ gcursor,
                               unsigned* __restrict__ startsKey) {
    __shared__ unsigned s[NCB_TOT + 1];
    int t = threadIdx.x;
    for (int j = t; j < NCB_TOT; j += 256) s[j] = gcnt[j];
    __syncthreads();
    if (t == 0) {
        unsigned run = 0;
        for (int j = 0; j < NCB_TOT; j++) { unsigned v = s[j]; s[j] = run; run += v; }
        s[NCB_TOT] = run;
    }
    __syncthreads();
    for (int j = t; j <= NCB_TOT; j += 256) {
        gstart[j] = s[j];
        if (j < NCB_TOT) gcursor[j] = s[j];
    }
    if (t == 0) startsKey[NKEY] = (unsigned)TOTAL_EDGES;
}

// ---- P3: tiled partition into 294 coarse buckets with coalesced staged flush ----
// rec: x = col (17b) | lrow10 (10b) << 17 ; y = val bits
__launch_bounds__(256)
__global__ void partition_kernel(const int* __restrict__ rows,
                                 const int* __restrict__ cols,
                                 const float* __restrict__ vals,
                                 unsigned* __restrict__ gcursor,
                                 uint2* __restrict__ recs) {
    __shared__ unsigned hist[NCB_TOT], lstart[NCB_TOT], gbase[NCB_TOT], lcur[NCB_TOT];
    __shared__ uint2 stag[TILE];           // 32 KB
    __shared__ unsigned short bkt[TILE];   // 8 KB
    int base = blockIdx.x * TILE;
    int cnt = TOTAL_EDGES - base; if (cnt > TILE) cnt = TILE;

    for (int j = threadIdx.x; j < NCB_TOT; j += 256) hist[j] = 0;
    __syncthreads();
    for (int t = threadIdx.x; t < cnt; t += 256) {
        int i = base + t;
        unsigned r = (unsigned)i / (unsigned)N_EDGES;
        unsigned cb = r * NCB + ((unsigned)rows[i] >> LOG_CB);
        atomicAdd(&hist[cb], 1u);
    }
    __syncthreads();
    if (threadIdx.x == 0) {
        unsigned run = 0;
        for (int j = 0; j < NCB_TOT; j++) { unsigned v = hist[j]; lstart[j] = run; lcur[j] = run; run += v; }
    }
    __syncthreads();
    for (int j = threadIdx.x; j < NCB_TOT; j += 256)
        if (hist[j]) gbase[j] = atomicAdd(&gcursor[j], hist[j]);
    __syncthreads();
    for (int t = threadIdx.x; t < cnt; t += 256) {
        int i = base + t;
        unsigned r = (unsigned)i / (unsigned)N_EDGES;
        unsigned row = (unsigned)rows[i];
        unsigned cb = r * NCB + (row >> LOG_CB);
        unsigned dst = atomicAdd(&lcur[cb], 1u);
        stag[dst] = make_uint2((unsigned)cols[i] | ((row & (CB_ROWS - 1)) << 17),
                               __float_as_uint(vals[i]));
        bkt[dst] = (unsigned short)cb;
    }
    __syncthreads();
    // flush: consecutive staged slots of a bucket -> consecutive global slots
    for (int t = threadIdx.x; t < cnt; t += 256) {
        unsigned b = bkt[t];
        recs[gbase[b] + ((unsigned)t - lstart[b])] = stag[t];
    }
}

// ---- P4: per-coarse-bucket exact-row CSR sort; emits recs2 + per-key starts ----
// Block owns its 256 KB output range exclusively -> full-line L2 writeback.
__launch_bounds__(256)
__global__ void bucket_sort_kernel(const uint2* __restrict__ recs,
                                   const unsigned* __restrict__ gstart,
                                   unsigned* __restrict__ startsKey,
                                   uint2* __restrict__ recs2) {
    __shared__ unsigned hist[CB_ROWS], cur[CB_ROWS];
    int cb = blockIdx.x;
    int rel = cb / NCB, cbi = cb % NCB;
    int row0 = cbi << LOG_CB;
    int nrows = N_ITEMS - row0; if (nrows > CB_ROWS) nrows = CB_ROWS;
    unsigned s0 = gstart[cb];
    int n = (int)(gstart[cb + 1] - s0);

    for (int j = threadIdx.x; j < CB_ROWS; j += 256) hist[j] = 0;
    __syncthreads();
    for (int t = threadIdx.x; t < n; t += 256) {
        unsigned lrow = recs[s0 + t].x >> 17;
        atomicAdd(&hist[lrow], 1u);
    }
    __syncthreads();
    if (threadIdx.x == 0) {
        unsigned run = 0;
        for (int j = 0; j < CB_ROWS; j++) { unsigned v = hist[j]; cur[j] = run; run += v; }
    }
    __syncthreads();
    unsigned keyBase = (unsigned)rel * N_ITEMS + (unsigned)row0;
    for (int j = threadIdx.x; j < nrows; j += 256) startsKey[keyBase + j] = s0 + cur[j];
    for (int t = threadIdx.x; t < n; t += 256) {
        uint2 rc = recs[s0 + t];
        unsigned lrow = rc.x >> 17;
        unsigned pos = s0 + atomicAdd(&cur[lrow], 1u);
        recs2[pos] = make_uint2(rc.x & 0x1FFFFu, rc.y);
    }
}

// ---- Phase B: atomic-free CSR gather (unchanged from R4/R5) ----
__launch_bounds__(192)
__global__ void gather_csr_kernel(const float* __restrict__ E,
                                  const unsigned* __restrict__ starts,
                                  const uint2* __restrict__ recs,
                                  float* __restrict__ out) {
    __shared__ float part[N_REL * EMBED_DIM];
    int row = blockIdx.x;
    int w = threadIdx.x >> 6;
    int d = threadIdx.x & 63;

    unsigned key = (unsigned)w * N_ITEMS + (unsigned)row;
    unsigned s = starts[key];
    int n = (int)(starts[key + 1] - s);
    const uint2* __restrict__ p = recs + s;

    float acc = 0.0f, deg = 0.0f;
    int j = 0;
    for (; j + 8 <= n; j += 8) {
        uint2 a[8];
        #pragma unroll
        for (int k = 0; k < 8; k++) a[k] = p[j + k];
        float e[8];
        #pragma unroll
        for (int k = 0; k < 8; k++) e[k] = E[a[k].x * EMBED_DIM + d];
        #pragma unroll
        for (int k = 0; k < 8; k++) {
            float wv = __uint_as_float(a[k].y);
            acc += wv * e[k];
            deg += wv;
        }
    }
    for (; j < n; j++) {
        uint2 a = p[j];
        float wv = __uint_as_float(a.y);
        acc += wv * E[a.x * EMBED_DIM + d];
        deg += wv;
    }

    part[w * EMBED_DIM + d] = acc / (3.0f * fmaxf(deg, 1.0f));
    __syncthreads();
    if (threadIdx.x < EMBED_DIM) {
        int gi = row * EMBED_DIM + threadIdx.x;
        out[gi] = E[gi] + part[threadIdx.x]
                        + part[EMBED_DIM + threadIdx.x]
                        + part[2 * EMBED_DIM + threadIdx.x];
    }
}

// ============================ v5 fallback (R5 pipeline) ============================
#define NBS ((NKEY + 255) / 256)

__global__ void hist300_kernel(const int* __restrict__ rows, unsigned* __restrict__ cnt) {
    int stride = gridDim.x * blockDim.x;
    for (int i = blockIdx.x * blockDim.x + threadIdx.x; i < TOTAL_EDGES; i += stride) {
        unsigned r = (unsigned)i / (unsigned)N_EDGES;
        unsigned key = r * N_ITEMS + (unsigned)rows[i];
        atomicAdd(&cnt[key], 1u);
    }
}

__global__ void scan_blocksum(const unsigned* __restrict__ cnt, unsigned* __restrict__ bsum) {
    __shared__ unsigned s[256];
    int i = blockIdx.x * 256 + threadIdx.x;
    s[threadIdx.x] = (i < NKEY) ? cnt[i] : 0u;
    __syncthreads();
    for (int off = 128; off > 0; off >>= 1) {
        if (threadIdx.x < off) s[threadIdx.x] += s[threadIdx.x + off];
        __syncthreads();
    }
    if (threadIdx.x == 0) bsum[blockIdx.x] = s[0];
}

__global__ void scan_partials(unsigned* __restrict__ bsum, unsigned* __restrict__ starts) {
    const int IT = 5;
    int t = threadIdx.x;
    unsigned loc[IT];
    unsigned sum = 0;
    #pragma unroll
    for (int k = 0; k < IT; k++) {
        int idx = t * IT + k;
        loc[k] = (idx < NBS) ? bsum[idx] : 0u;
        sum += loc[k];
    }
    int lane = t & 63, wid = t >> 6;
    unsigned inc = sum;
    #pragma unroll
    for (int d = 1; d < 64; d <<= 1) {
        unsigned x = __shfl_up(inc, d, 64);
        if (lane >= d) inc += x;
    }
    __shared__ unsigned woff[4], woffEx[4];
    if (lane == 63) woff[wid] = inc;
    __syncthreads();
    if (t == 0) { unsigned run = 0; for (int k = 0; k < 4; k++) { woffEx[k] = run; run += woff[k]; } }
    __syncthreads();
    unsigned ex = inc - sum + woffEx[wid];
    #pragma unroll
    for (int k = 0; k < IT; k++) {
        int idx = t * IT + k;
        if (idx < NBS) { bsum[idx] = ex; ex += loc[k]; }
    }
    if (t == 0) starts[NKEY] = (unsigned)TOTAL_EDGES;
}

__global__ void scan_final(unsigned* key_arr,
                           const unsigned* __restrict__ bsum,
                           unsigned* __restrict__ cursor) {
    int i = blockIdx.x * 256 + threadIdx.x;
    unsigned v = (i < NKEY) ? key_arr[i] : 0u;
    int lane = threadIdx.x & 63, wid = threadIdx.x >> 6;
    unsigned inc = v;
    #pragma unroll
    for (int d = 1; d < 64; d <<= 1) {
        unsigned x = __shfl_up(inc, d, 64);
        if (lane >= d) inc += x;
    }
    __shared__ unsigned woff[4], woffEx[4];
    if (lane == 63) woff[wid] = inc;
    __syncthreads();
    if (threadIdx.x == 0) { unsigned run = 0; for (int k = 0; k < 4; k++) { woffEx[k] = run; run += woff[k]; } }
    __syncthreads();
    unsigned ex = inc - v + woffEx[wid] + bsum[blockIdx.x];
    if (i < NKEY) { key_arr[i] = ex; cursor[i] = ex; }
}

__global__ void binscatter2_kernel(const int* __restrict__ rows,
                                   const int* __restrict__ cols,
                                   const float* __restrict__ vals,
                                   unsigned* __restrict__ cursor,
                                   uint2* __restrict__ recs) {
    int stride = gridDim.x * blockDim.x;
    for (int i = blockIdx.x * blockDim.x + threadIdx.x; i < TOTAL_EDGES; i += stride) {
        unsigned r = (unsigned)i / (unsigned)N_EDGES;
        unsigned key = r * N_ITEMS + (unsigned)rows[i];
        unsigned pos = atomicAdd(&cursor[key], 1u);
        uint2 rec;
        rec.x = (unsigned)cols[i];
        rec.y = __float_as_uint(vals[i]);
        recs[pos] = rec;
    }
}

// ============================ R1 fallback ============================
__global__ void deg_kernel(const int* __restrict__ rows,
                           const float* __restrict__ vals,
                           float* __restrict__ deg) {
    long long i = (long long)blockIdx.x * blockDim.x + threadIdx.x;
    if (i >= TOTAL_EDGES) return;
    int r = (int)(i / N_EDGES);
    int row = rows[i];
    atomicAdd(&deg[(long long)r * N_ITEMS + row], vals[i]);
}

__global__ void inv_kernel(float* __restrict__ deg) {
    int i = blockIdx.x * blockDim.x + threadIdx.x;
    if (i >= N_REL * N_ITEMS) return;
    float d = deg[i];
    d = fmaxf(d, 1.0f);
    deg[i] = 1.0f / (3.0f * d);
}

__global__ void scatter_kernel(const float* __restrict__ E,
                               const int* __restrict__ rows,
                               const int* __restrict__ cols,
                               const float* __restrict__ vals,
                               const float* __restrict__ inv,
                               float* __restrict__ out) {
    long long t = (long long)blockIdx.x * blockDim.x + threadIdx.x;
    long long edge = t >> 6;
    int d = (int)(t & 63);
    if (edge >= TOTAL_EDGES) return;
    int r = (int)(edge / N_EDGES);
    int row = rows[edge];
    int col = cols[edge];
    float w = vals[edge] * inv[r * N_ITEMS + row];
    float msg = w * E[(long long)col * EMBED_DIM + d];
    atomicAdd(&out[(long long)row * EMBED_DIM + d], msg);
}

// ============================ launcher ============================
extern "C" void kernel_launch(void* const* d_in, const int* in_sizes, int n_in,
                              void* d_out, int out_size, void* d_ws, size_t ws_size,
                              hipStream_t stream) {
    const float* E    = (const float*)d_in[0];
    const int*   rows = (const int*)d_in[1];
    const int*   cols = (const int*)d_in[2];
    const float* vals = (const float*)d_in[3];
    float* out = (float*)d_out;

    // v6 workspace: startsKey[NKEY+1] | gcnt | gstart | gcursor | recs | recs2
    const size_t REGA = 1204224;                         // >= (NKEY+1)*4
    const size_t REGS = 4096;                            // small arrays
    const size_t RECB = (size_t)TOTAL_EDGES * sizeof(uint2);  // 76.8 MB
    size_t need6 = REGA + 3 * REGS + 2 * RECB;

    // v5 workspace: keyA[NKEY+1] | cursor[NKEY] | bsum | recs
    const size_t REGC = 8192;
    size_t need5 = 2 * REGA + REGC + RECB;

    if (ws_size >= need6) {
        unsigned* startsKey = (unsigned*)d_ws;
        unsigned* gcnt      = (unsigned*)((char*)d_ws + REGA);
        unsigned* gstart    = (unsigned*)((char*)d_ws + REGA + REGS);
        unsigned* gcursor   = (unsigned*)((char*)d_ws + REGA + 2 * REGS);
        uint2*    recs      = (uint2*)((char*)d_ws + REGA + 3 * REGS);
        uint2*    recs2     = (uint2*)((char*)d_ws + REGA + 3 * REGS + RECB);

        hipMemsetAsync(gcnt, 0, NCB_TOT * sizeof(unsigned), stream);
        hist294_kernel<<<1172, 256, 0, stream>>>(rows, gcnt);
        scan294_kernel<<<1, 256, 0, stream>>>(gcnt, gstart, gcursor, startsKey);
        partition_kernel<<<(TOTAL_EDGES + TILE - 1) / TILE, 256, 0, stream>>>(
            rows, cols, vals, gcursor, recs);
        bucket_sort_kernel<<<NCB_TOT, 256, 0, stream>>>(recs, gstart, startsKey, recs2);
        gather_csr_kernel<<<N_ITEMS, 192, 0, stream>>>(E, startsKey, recs2, out);
    } else if (ws_size >= need5) {
        unsigned* keyA   = (unsigned*)d_ws;
        unsigned* cursor = (unsigned*)((char*)d_ws + REGA);
        unsigned* bsum   = (unsigned*)((char*)d_ws + 2 * REGA);
        uint2*    recs   = (uint2*)((char*)d_ws + 2 * REGA + REGC);

        hipMemsetAsync(keyA, 0, NKEY * sizeof(unsigned), stream);
        hist300_kernel<<<1536, 256, 0, stream>>>(rows, keyA);
        scan_blocksum<<<NBS, 256, 0, stream>>>(keyA, bsum);
        scan_partials<<<1, 256, 0, stream>>>(bsum, keyA);
        scan_final<<<NBS, 256, 0, stream>>>(keyA, bsum, cursor);
        binscatter2_kernel<<<2048, 256, 0, stream>>>(rows, cols, vals, cursor, recs);
        gather_csr_kernel<<<N_ITEMS, 192, 0, stream>>>(E, keyA, recs, out);
    } else {
        float* deg = (float*)d_ws;
        hipMemsetAsync(deg, 0, (size_t)N_REL * N_ITEMS * sizeof(float), stream);
        {
            long long total = TOTAL_EDGES;
            int block = 256;
            long long grid = (total + block - 1) / block;
            deg_kernel<<<(unsigned)grid, block, 0, stream>>>(rows, vals, deg);
        }
        {
            int total = N_REL * N_ITEMS;
            int block = 256;
            int grid = (total + block - 1) / block;
            inv_kernel<<<grid, block, 0, stream>>>(deg);
        }
        hipMemcpyAsync(out, E, (size_t)N_ITEMS * EMBED_DIM * sizeof(float),
                       hipMemcpyDeviceToDevice, stream);
        {
            long long threads = (long long)TOTAL_EDGES * 64;
            int block = 256;
            long long grid = (threads + block - 1) / block;
            scatter_kernel<<<(unsigned)grid, block, 0, stream>>>(E, rows, cols, vals, deg, out);
        }
    }
}

// Round 7
// 682.500 us; speedup vs baseline: 6.0874x; 1.1510x over previous
//
#include <hip/hip_runtime.h>

// Problem constants (from reference)
#define N_ITEMS     100000
#define EMBED_DIM   64
#define N_REL       3
#define N_EDGES     3200000
#define TOTAL_EDGES (N_REL * N_EDGES)   // 9,600,000 (fits int)
#define NKEY        (N_REL * N_ITEMS)   // 300,000 exact (rel,row) segments

// Coarse buckets: 1024 rows each -> 98 per relation, 294 total
#define LOG_CB   10
#define CB_ROWS  1024
#define NCB      98
#define NCB_TOT  (N_REL * NCB)          // 294
#define TILE     4096                   // edges staged per partition block

// ============================ v7 pipeline ============================

// ---- P1: global histogram over 294 coarse buckets (LDS-privatized) ----
__global__ void hist294_kernel(const int* __restrict__ rows, unsigned* __restrict__ gcnt) {
    __shared__ unsigned h[NCB_TOT];
    for (int j = threadIdx.x; j < NCB_TOT; j += 256) h[j] = 0;
    __syncthreads();
    int stride = gridDim.x * blockDim.x;
    for (int i = blockIdx.x * blockDim.x + threadIdx.x; i < TOTAL_EDGES; i += stride) {
        unsigned r = (unsigned)i / (unsigned)N_EDGES;
        unsigned cb = r * NCB + ((unsigned)rows[i] >> LOG_CB);
        atomicAdd(&h[cb], 1u);
    }
    __syncthreads();
    for (int j = threadIdx.x; j < NCB_TOT; j += 256)
        if (h[j]) atomicAdd(&gcnt[j], h[j]);
}

// ---- P2: scan 294 counts -> gstart[295], gcursor[294]; seed startsKey[NKEY] ----
__global__ void scan294_kernel(const unsigned* __restrict__ gcnt,
                               unsigned* __restrict__ gstart,
                               unsigned* __restrict__ gcursor,
                               unsigned* __restrict__ startsKey) {
    __shared__ unsigned s[NCB_TOT + 1];
    int t = threadIdx.x;
    for (int j = t; j < NCB_TOT; j += 256) s[j] = gcnt[j];
    __syncthreads();
    if (t == 0) {
        unsigned run = 0;
        for (int j = 0; j < NCB_TOT; j++) { unsigned v = s[j]; s[j] = run; run += v; }
        s[NCB_TOT] = run;
    }
    __syncthreads();
    for (int j = t; j <= NCB_TOT; j += 256) {
        gstart[j] = s[j];
        if (j < NCB_TOT) gcursor[j] = s[j];
    }
    if (t == 0) startsKey[NKEY] = (unsigned)TOTAL_EDGES;
}

// ---- P3: tiled partition into 294 coarse buckets with coalesced staged flush ----
// rec: x = col (17b) | lrow10 (10b) << 17 ; y = val bits
__launch_bounds__(256)
__global__ void partition_kernel(const int* __restrict__ rows,
                                 const int* __restrict__ cols,
                                 const float* __restrict__ vals,
                                 unsigned* __restrict__ gcursor,
                                 uint2* __restrict__ recs) {
    __shared__ unsigned hist[NCB_TOT], lstart[NCB_TOT], gbase[NCB_TOT], lcur[NCB_TOT];
    __shared__ uint2 stag[TILE];           // 32 KB
    __shared__ unsigned short bkt[TILE];   // 8 KB
    int base = blockIdx.x * TILE;
    int cnt = TOTAL_EDGES - base; if (cnt > TILE) cnt = TILE;

    for (int j = threadIdx.x; j < NCB_TOT; j += 256) hist[j] = 0;
    __syncthreads();
    for (int t = threadIdx.x; t < cnt; t += 256) {
        int i = base + t;
        unsigned r = (unsigned)i / (unsigned)N_EDGES;
        unsigned cb = r * NCB + ((unsigned)rows[i] >> LOG_CB);
        atomicAdd(&hist[cb], 1u);
    }
    __syncthreads();
    if (threadIdx.x == 0) {
        unsigned run = 0;
        for (int j = 0; j < NCB_TOT; j++) { unsigned v = hist[j]; lstart[j] = run; lcur[j] = run; run += v; }
    }
    __syncthreads();
    for (int j = threadIdx.x; j < NCB_TOT; j += 256)
        if (hist[j]) gbase[j] = atomicAdd(&gcursor[j], hist[j]);
    __syncthreads();
    for (int t = threadIdx.x; t < cnt; t += 256) {
        int i = base + t;
        unsigned r = (unsigned)i / (unsigned)N_EDGES;
        unsigned row = (unsigned)rows[i];
        unsigned cb = r * NCB + (row >> LOG_CB);
        unsigned dst = atomicAdd(&lcur[cb], 1u);
        stag[dst] = make_uint2((unsigned)cols[i] | ((row & (CB_ROWS - 1)) << 17),
                               __float_as_uint(vals[i]));
        bkt[dst] = (unsigned short)cb;
    }
    __syncthreads();
    // flush: consecutive staged slots of a bucket -> consecutive global slots
    for (int t = threadIdx.x; t < cnt; t += 256) {
        unsigned b = bkt[t];
        recs[gbase[b] + ((unsigned)t - lstart[b])] = stag[t];
    }
}

// ---- P4: per-coarse-bucket exact-row CSR sort (1024 thr, parallel scan) ----
// Block owns its 256 KB output range exclusively -> full-line L2 writeback.
__launch_bounds__(1024)
__global__ void bucket_sort_kernel(const uint2* __restrict__ recs,
                                   const unsigned* __restrict__ gstart,
                                   unsigned* __restrict__ startsKey,
                                   uint2* __restrict__ recs2) {
    __shared__ unsigned hist[CB_ROWS], cur[CB_ROWS], wsum[16];
    int cb = blockIdx.x;
    int t = threadIdx.x;
    int rel = cb / NCB, cbi = cb % NCB;
    int row0 = cbi << LOG_CB;
    int nrows = N_ITEMS - row0; if (nrows > CB_ROWS) nrows = CB_ROWS;
    unsigned s0 = gstart[cb];
    int n = (int)(gstart[cb + 1] - s0);

    hist[t] = 0;
    __syncthreads();
    for (int i = t; i < n; i += 1024)
        atomicAdd(&hist[recs[s0 + i].x >> 17], 1u);
    __syncthreads();

    // parallel exclusive scan of 1024 counters
    unsigned v = hist[t];
    int lane = t & 63, wid = t >> 6;
    unsigned inc = v;
    #pragma unroll
    for (int dd = 1; dd < 64; dd <<= 1) {
        unsigned x = __shfl_up(inc, dd, 64);
        if (lane >= dd) inc += x;
    }
    if (lane == 63) wsum[wid] = inc;
    __syncthreads();
    if (t == 0) {
        unsigned run = 0;
        for (int k = 0; k < 16; k++) { unsigned x = wsum[k]; wsum[k] = run; run += x; }
    }
    __syncthreads();
    unsigned ex = inc - v + wsum[wid];
    cur[t] = ex;
    if (t < nrows) startsKey[(unsigned)rel * N_ITEMS + (unsigned)row0 + t] = s0 + ex;
    __syncthreads();

    for (int i = t; i < n; i += 1024) {
        uint2 rc = recs[s0 + i];
        unsigned lrow = rc.x >> 17;
        unsigned pos = s0 + atomicAdd(&cur[lrow], 1u);
        recs2[pos] = make_uint2(rc.x & 0x1FFFFu, rc.y);
    }
}

// ---- P5: E -> bf16 copy (gather input only; residual stays fp32) ----
__global__ void tobf16_kernel(const float* __restrict__ E, unsigned short* __restrict__ Ebf) {
    int i = blockIdx.x * 256 + threadIdx.x;
    if (i < N_ITEMS * EMBED_DIM) {
        unsigned u = __float_as_uint(E[i]);
        unsigned r = (u + 0x7FFFu + ((u >> 16) & 1u)) >> 16;  // RNE
        Ebf[i] = (unsigned short)r;
    }
}

// ---- Phase B: atomic-free CSR gather, bf16 E, 16-deep load batches ----
__launch_bounds__(192)
__global__ void gather_csr_kernel(const unsigned short* __restrict__ Ebf,
                                  const float* __restrict__ E,
                                  const unsigned* __restrict__ starts,
                                  const uint2* __restrict__ recs,
                                  float* __restrict__ out) {
    __shared__ float part[N_REL * EMBED_DIM];
    int row = blockIdx.x;
    int w = threadIdx.x >> 6;
    int d = threadIdx.x & 63;

    unsigned key = (unsigned)w * N_ITEMS + (unsigned)row;
    unsigned s = starts[key];
    int n = (int)(starts[key + 1] - s);
    const uint2* __restrict__ p = recs + s;

    float acc = 0.0f, deg = 0.0f;
    int j = 0;
    for (; j + 16 <= n; j += 16) {
        uint2 a[16];
        #pragma unroll
        for (int k = 0; k < 16; k++) a[k] = p[j + k];
        float e[16];
        #pragma unroll
        for (int k = 0; k < 16; k++)
            e[k] = __uint_as_float((unsigned)Ebf[a[k].x * EMBED_DIM + d] << 16);
        #pragma unroll
        for (int k = 0; k < 16; k++) {
            float wv = __uint_as_float(a[k].y);
            acc += wv * e[k];
            deg += wv;
        }
    }
    for (; j + 4 <= n; j += 4) {
        uint2 a[4];
        #pragma unroll
        for (int k = 0; k < 4; k++) a[k] = p[j + k];
        float e[4];
        #pragma unroll
        for (int k = 0; k < 4; k++)
            e[k] = __uint_as_float((unsigned)Ebf[a[k].x * EMBED_DIM + d] << 16);
        #pragma unroll
        for (int k = 0; k < 4; k++) {
            float wv = __uint_as_float(a[k].y);
            acc += wv * e[k];
            deg += wv;
        }
    }
    for (; j < n; j++) {
        uint2 a = p[j];
        float wv = __uint_as_float(a.y);
        acc += wv * __uint_as_float((unsigned)Ebf[a.x * EMBED_DIM + d] << 16);
        deg += wv;
    }

    part[w * EMBED_DIM + d] = acc / (3.0f * fmaxf(deg, 1.0f));
    __syncthreads();
    if (threadIdx.x < EMBED_DIM) {
        int gi = row * EMBED_DIM + threadIdx.x;
        out[gi] = E[gi] + part[threadIdx.x]
                        + part[EMBED_DIM + threadIdx.x]
                        + part[2 * EMBED_DIM + threadIdx.x];
    }
}

// ============================ v5 fallback (R5 pipeline) ============================
#define NBS ((NKEY + 255) / 256)

__global__ void hist300_kernel(const int* __restrict__ rows, unsigned* __restrict__ cnt) {
    int stride = gridDim.x * blockDim.x;
    for (int i = blockIdx.x * blockDim.x + threadIdx.x; i < TOTAL_EDGES; i += stride) {
        unsigned r = (unsigned)i / (unsigned)N_EDGES;
        unsigned key = r * N_ITEMS + (unsigned)rows[i];
        atomicAdd(&cnt[key], 1u);
    }
}

__global__ void scan_blocksum(const unsigned* __restrict__ cnt, unsigned* __restrict__ bsum) {
    __shared__ unsigned s[256];
    int i = blockIdx.x * 256 + threadIdx.x;
    s[threadIdx.x] = (i < NKEY) ? cnt[i] : 0u;
    __syncthreads();
    for (int off = 128; off > 0; off >>= 1) {
        if (threadIdx.x < off) s[threadIdx.x] += s[threadIdx.x + off];
        __syncthreads();
    }
    if (threadIdx.x == 0) bsum[blockIdx.x] = s[0];
}

__global__ void scan_partials(unsigned* __restrict__ bsum, unsigned* __restrict__ starts) {
    const int IT = 5;
    int t = threadIdx.x;
    unsigned loc[IT];
    unsigned sum = 0;
    #pragma unroll
    for (int k = 0; k < IT; k++) {
        int idx = t * IT + k;
        loc[k] = (idx < NBS) ? bsum[idx] : 0u;
        sum += loc[k];
    }
    int lane = t & 63, wid = t >> 6;
    unsigned inc = sum;
    #pragma unroll
    for (int d = 1; d < 64; d <<= 1) {
        unsigned x = __shfl_up(inc, d, 64);
        if (lane >= d) inc += x;
    }
    __shared__ unsigned woff[4], woffEx[4];
    if (lane == 63) woff[wid] = inc;
    __syncthreads();
    if (t == 0) { unsigned run = 0; for (int k = 0; k < 4; k++) { woffEx[k] = run; run += woff[k]; } }
    __syncthreads();
    unsigned ex = inc - sum + woffEx[wid];
    #pragma unroll
    for (int k = 0; k < IT; k++) {
        int idx = t * IT + k;
        if (idx < NBS) { bsum[idx] = ex; ex += loc[k]; }
    }
    if (t == 0) starts[NKEY] = (unsigned)TOTAL_EDGES;
}

__global__ void scan_final(unsigned* key_arr,
                           const unsigned* __restrict__ bsum,
                           unsigned* __restrict__ cursor) {
    int i = blockIdx.x * 256 + threadIdx.x;
    unsigned v = (i < NKEY) ? key_arr[i] : 0u;
    int lane = threadIdx.x & 63, wid = threadIdx.x >> 6;
    unsigned inc = v;
    #pragma unroll
    for (int d = 1; d < 64; d <<= 1) {
        unsigned x = __shfl_up(inc, d, 64);
        if (lane >= d) inc += x;
    }
    __shared__ unsigned woff[4], woffEx[4];
    if (lane == 63) woff[wid] = inc;
    __syncthreads();
    if (threadIdx.x == 0) { unsigned run = 0; for (int k = 0; k < 4; k++) { woffEx[k] = run; run += woff[k]; } }
    __syncthreads();
    unsigned ex = inc - v + woffEx[wid] + bsum[blockIdx.x];
    if (i < NKEY) { key_arr[i] = ex; cursor[i] = ex; }
}

__global__ void binscatter2_kernel(const int* __restrict__ rows,
                                   const int* __restrict__ cols,
                                   const float* __restrict__ vals,
                                   unsigned* __restrict__ cursor,
                                   uint2* __restrict__ recs) {
    int stride = gridDim.x * blockDim.x;
    for (int i = blockIdx.x * blockDim.x + threadIdx.x; i < TOTAL_EDGES; i += stride) {
        unsigned r = (unsigned)i / (unsigned)N_EDGES;
        unsigned key = r * N_ITEMS + (unsigned)rows[i];
        unsigned pos = atomicAdd(&cursor[key], 1u);
        uint2 rec;
        rec.x = (unsigned)cols[i];
        rec.y = __float_as_uint(vals[i]);
        recs[pos] = rec;
    }
}

// fp32-E gather for the v5 fallback
__launch_bounds__(192)
__global__ void gather_csr_f32_kernel(const float* __restrict__ E,
                                      const unsigned* __restrict__ starts,
                                      const uint2* __restrict__ recs,
                                      float* __restrict__ out) {
    __shared__ float part[N_REL * EMBED_DIM];
    int row = blockIdx.x;
    int w = threadIdx.x >> 6;
    int d = threadIdx.x & 63;
    unsigned key = (unsigned)w * N_ITEMS + (unsigned)row;
    unsigned s = starts[key];
    int n = (int)(starts[key + 1] - s);
    const uint2* __restrict__ p = recs + s;
    float acc = 0.0f, deg = 0.0f;
    int j = 0;
    for (; j + 8 <= n; j += 8) {
        uint2 a[8];
        #pragma unroll
        for (int k = 0; k < 8; k++) a[k] = p[j + k];
        float e[8];
        #pragma unroll
        for (int k = 0; k < 8; k++) e[k] = E[a[k].x * EMBED_DIM + d];
        #pragma unroll
        for (int k = 0; k < 8; k++) {
            float wv = __uint_as_float(a[k].y);
            acc += wv * e[k];
            deg += wv;
        }
    }
    for (; j < n; j++) {
        uint2 a = p[j];
        float wv = __uint_as_float(a.y);
        acc += wv * E[a.x * EMBED_DIM + d];
        deg += wv;
    }
    part[w * EMBED_DIM + d] = acc / (3.0f * fmaxf(deg, 1.0f));
    __syncthreads();
    if (threadIdx.x < EMBED_DIM) {
        int gi = row * EMBED_DIM + threadIdx.x;
        out[gi] = E[gi] + part[threadIdx.x]
                        + part[EMBED_DIM + threadIdx.x]
                        + part[2 * EMBED_DIM + threadIdx.x];
    }
}

// ============================ R1 fallback ============================
__global__ void deg_kernel(const int* __restrict__ rows,
                           const float* __restrict__ vals,
                           float* __restrict__ deg) {
    long long i = (long long)blockIdx.x * blockDim.x + threadIdx.x;
    if (i >= TOTAL_EDGES) return;
    int r = (int)(i / N_EDGES);
    int row = rows[i];
    atomicAdd(&deg[(long long)r * N_ITEMS + row], vals[i]);
}

__global__ void inv_kernel(float* __restrict__ deg) {
    int i = blockIdx.x * blockDim.x + threadIdx.x;
    if (i >= N_REL * N_ITEMS) return;
    float d = deg[i];
    d = fmaxf(d, 1.0f);
    deg[i] = 1.0f / (3.0f * d);
}

__global__ void scatter_kernel(const float* __restrict__ E,
                               const int* __restrict__ rows,
                               const int* __restrict__ cols,
                               const float* __restrict__ vals,
                               const float* __restrict__ inv,
                               float* __restrict__ out) {
    long long t = (long long)blockIdx.x * blockDim.x + threadIdx.x;
    long long edge = t >> 6;
    int d = (int)(t & 63);
    if (edge >= TOTAL_EDGES) return;
    int r = (int)(edge / N_EDGES);
    int row = rows[edge];
    int col = cols[edge];
    float w = vals[edge] * inv[r * N_ITEMS + row];
    float msg = w * E[(long long)col * EMBED_DIM + d];
    atomicAdd(&out[(long long)row * EMBED_DIM + d], msg);
}

// ============================ launcher ============================
extern "C" void kernel_launch(void* const* d_in, const int* in_sizes, int n_in,
                              void* d_out, int out_size, void* d_ws, size_t ws_size,
                              hipStream_t stream) {
    const float* E    = (const float*)d_in[0];
    const int*   rows = (const int*)d_in[1];
    const int*   cols = (const int*)d_in[2];
    const float* vals = (const float*)d_in[3];
    float* out = (float*)d_out;

    // v7 workspace: startsKey[NKEY+1] | gcnt | gstart | gcursor | recs | recs2
    // Ebf (12.8 MB) reuses the recs buffer after bucket_sort no longer needs it.
    const size_t REGA = 1204224;                              // >= (NKEY+1)*4
    const size_t REGS = 4096;                                 // small arrays
    const size_t RECB = (size_t)TOTAL_EDGES * sizeof(uint2);  // 76.8 MB
    size_t need7 = REGA + 3 * REGS + 2 * RECB;

    const size_t REGC = 8192;
    size_t need5 = 2 * REGA + REGC + RECB;

    if (ws_size >= need7) {
        unsigned* startsKey = (unsigned*)d_ws;
        unsigned* gcnt      = (unsigned*)((char*)d_ws + REGA);
        unsigned* gstart    = (unsigned*)((char*)d_ws + REGA + REGS);
        unsigned* gcursor   = (unsigned*)((char*)d_ws + REGA + 2 * REGS);
        uint2*    recs      = (uint2*)((char*)d_ws + REGA + 3 * REGS);
        uint2*    recs2     = (uint2*)((char*)d_ws + REGA + 3 * REGS + RECB);
        unsigned short* Ebf = (unsigned short*)recs;  // reuse after bucket_sort

        hipMemsetAsync(gcnt, 0, NCB_TOT * sizeof(unsigned), stream);
        hist294_kernel<<<1172, 256, 0, stream>>>(rows, gcnt);
        scan294_kernel<<<1, 256, 0, stream>>>(gcnt, gstart, gcursor, startsKey);
        partition_kernel<<<(TOTAL_EDGES + TILE - 1) / TILE, 256, 0, stream>>>(
            rows, cols, vals, gcursor, recs);
        bucket_sort_kernel<<<NCB_TOT, 1024, 0, stream>>>(recs, gstart, startsKey, recs2);
        tobf16_kernel<<<(N_ITEMS * EMBED_DIM + 255) / 256, 256, 0, stream>>>(E, Ebf);
        gather_csr_kernel<<<N_ITEMS, 192, 0, stream>>>(Ebf, E, startsKey, recs2, out);
    } else if (ws_size >= need5) {
        unsigned* keyA   = (unsigned*)d_ws;
        unsigned* cursor = (unsigned*)((char*)d_ws + REGA);
        unsigned* bsum   = (unsigned*)((char*)d_ws + 2 * REGA);
        uint2*    recs   = (uint2*)((char*)d_ws + 2 * REGA + REGC);

        hipMemsetAsync(keyA, 0, NKEY * sizeof(unsigned), stream);
        hist300_kernel<<<1536, 256, 0, stream>>>(rows, keyA);
        scan_blocksum<<<NBS, 256, 0, stream>>>(keyA, bsum);
        scan_partials<<<1, 256, 0, stream>>>(bsum, keyA);
        scan_final<<<NBS, 256, 0, stream>>>(keyA, bsum, cursor);
        binscatter2_kernel<<<2048, 256, 0, stream>>>(rows, cols, vals, cursor, recs);
        gather_csr_f32_kernel<<<N_ITEMS, 192, 0, stream>>>(E, keyA, recs, out);
    } else {
        float* deg = (float*)d_ws;
        hipMemsetAsync(deg, 0, (size_t)N_REL * N_ITEMS * sizeof(float), stream);
        {
            long long total = TOTAL_EDGES;
            int block = 256;
            long long grid = (total + block - 1) / block;
            deg_kernel<<<(unsigned)grid, block, 0, stream>>>(rows, vals, deg);
        }
        {
            int total = N_REL * N_ITEMS;
            int block = 256;
            int grid = (total + block - 1) / block;
            inv_kernel<<<grid, block, 0, stream>>>(deg);
        }
        hipMemcpyAsync(out, E, (size_t)N_ITEMS * EMBED_DIM * sizeof(float),
                       hipMemcpyDeviceToDevice, stream);
        {
            long long threads = (long long)TOTAL_EDGES * 64;
            int block = 256;
            long long grid = (threads + block - 1) / block;
            scatter_kernel<<<(unsigned)grid, block, 0, stream>>>(E, rows, cols, vals, deg, out);
        }
    }
}

// Round 8
// 632.781 us; speedup vs baseline: 6.5657x; 1.0786x over previous
//
#include <hip/hip_runtime.h>

// Problem constants (from reference)
#define N_ITEMS     100000
#define EMBED_DIM   64
#define N_REL       3
#define N_EDGES     3200000
#define TOTAL_EDGES (N_REL * N_EDGES)   // 9,600,000 (fits int)
#define NKEY        (N_REL * N_ITEMS)   // 300,000 exact (rel,row) segments

// Coarse buckets: 1024 rows each -> 98 per relation, 294 total
#define LOG_CB   10
#define CB_ROWS  1024
#define NCB      98
#define NCB_TOT  (N_REL * NCB)          // 294
#define TILE     4096                   // edges staged per partition block

// ============================ v8 pipeline ============================

// ---- P1: global histogram over 294 coarse buckets (LDS-privatized) ----
__global__ void hist294_kernel(const int* __restrict__ rows, unsigned* __restrict__ gcnt) {
    __shared__ unsigned h[NCB_TOT];
    for (int j = threadIdx.x; j < NCB_TOT; j += 256) h[j] = 0;
    __syncthreads();
    int stride = gridDim.x * blockDim.x;
    for (int i = blockIdx.x * blockDim.x + threadIdx.x; i < TOTAL_EDGES; i += stride) {
        unsigned r = (unsigned)i / (unsigned)N_EDGES;
        unsigned cb = r * NCB + ((unsigned)rows[i] >> LOG_CB);
        atomicAdd(&h[cb], 1u);
    }
    __syncthreads();
    for (int j = threadIdx.x; j < NCB_TOT; j += 256)
        if (h[j]) atomicAdd(&gcnt[j], h[j]);
}

// ---- P2: scan 294 counts -> gstart[295], gcursor[294]; seed startsKey[NKEY] ----
__global__ void scan294_kernel(const unsigned* __restrict__ gcnt,
                               unsigned* __restrict__ gstart,
                               unsigned* __restrict__ gcursor,
                               unsigned* __restrict__ startsKey) {
    __shared__ unsigned s[NCB_TOT + 1];
    int t = threadIdx.x;
    for (int j = t; j < NCB_TOT; j += 256) s[j] = gcnt[j];
    __syncthreads();
    if (t == 0) {
        unsigned run = 0;
        for (int j = 0; j < NCB_TOT; j++) { unsigned v = s[j]; s[j] = run; run += v; }
        s[NCB_TOT] = run;
    }
    __syncthreads();
    for (int j = t; j <= NCB_TOT; j += 256) {
        gstart[j] = s[j];
        if (j < NCB_TOT) gcursor[j] = s[j];
    }
    if (t == 0) startsKey[NKEY] = (unsigned)TOTAL_EDGES;
}

// ---- P3: tiled partition into 294 coarse buckets with coalesced staged flush ----
// rec: x = col (17b) | lrow10 (10b) << 17 ; y = val bits
__launch_bounds__(256)
__global__ void partition_kernel(const int* __restrict__ rows,
                                 const int* __restrict__ cols,
                                 const float* __restrict__ vals,
                                 unsigned* __restrict__ gcursor,
                                 uint2* __restrict__ recs) {
    __shared__ unsigned hist[NCB_TOT], lstart[NCB_TOT], gbase[NCB_TOT], lcur[NCB_TOT];
    __shared__ uint2 stag[TILE];           // 32 KB
    __shared__ unsigned short bkt[TILE];   // 8 KB
    int base = blockIdx.x * TILE;
    int cnt = TOTAL_EDGES - base; if (cnt > TILE) cnt = TILE;

    for (int j = threadIdx.x; j < NCB_TOT; j += 256) hist[j] = 0;
    __syncthreads();
    for (int t = threadIdx.x; t < cnt; t += 256) {
        int i = base + t;
        unsigned r = (unsigned)i / (unsigned)N_EDGES;
        unsigned cb = r * NCB + ((unsigned)rows[i] >> LOG_CB);
        atomicAdd(&hist[cb], 1u);
    }
    __syncthreads();
    if (threadIdx.x == 0) {
        unsigned run = 0;
        for (int j = 0; j < NCB_TOT; j++) { unsigned v = hist[j]; lstart[j] = run; lcur[j] = run; run += v; }
    }
    __syncthreads();
    for (int j = threadIdx.x; j < NCB_TOT; j += 256)
        if (hist[j]) gbase[j] = atomicAdd(&gcursor[j], hist[j]);
    __syncthreads();
    for (int t = threadIdx.x; t < cnt; t += 256) {
        int i = base + t;
        unsigned r = (unsigned)i / (unsigned)N_EDGES;
        unsigned row = (unsigned)rows[i];
        unsigned cb = r * NCB + (row >> LOG_CB);
        unsigned dst = atomicAdd(&lcur[cb], 1u);
        stag[dst] = make_uint2((unsigned)cols[i] | ((row & (CB_ROWS - 1)) << 17),
                               __float_as_uint(vals[i]));
        bkt[dst] = (unsigned short)cb;
    }
    __syncthreads();
    // flush: consecutive staged slots of a bucket -> consecutive global slots
    for (int t = threadIdx.x; t < cnt; t += 256) {
        unsigned b = bkt[t];
        recs[gbase[b] + ((unsigned)t - lstart[b])] = stag[t];
    }
}

// ---- P4: per-coarse-bucket exact-row CSR sort (1024 thr, parallel scan) ----
// Block owns its 256 KB output range exclusively -> full-line L2 writeback.
__launch_bounds__(1024)
__global__ void bucket_sort_kernel(const uint2* __restrict__ recs,
                                   const unsigned* __restrict__ gstart,
                                   unsigned* __restrict__ startsKey,
                                   uint2* __restrict__ recs2) {
    __shared__ unsigned hist[CB_ROWS], cur[CB_ROWS], wsum[16];
    int cb = blockIdx.x;
    int t = threadIdx.x;
    int rel = cb / NCB, cbi = cb % NCB;
    int row0 = cbi << LOG_CB;
    int nrows = N_ITEMS - row0; if (nrows > CB_ROWS) nrows = CB_ROWS;
    unsigned s0 = gstart[cb];
    int n = (int)(gstart[cb + 1] - s0);

    hist[t] = 0;
    __syncthreads();
    for (int i = t; i < n; i += 1024)
        atomicAdd(&hist[recs[s0 + i].x >> 17], 1u);
    __syncthreads();

    // parallel exclusive scan of 1024 counters
    unsigned v = hist[t];
    int lane = t & 63, wid = t >> 6;
    unsigned inc = v;
    #pragma unroll
    for (int dd = 1; dd < 64; dd <<= 1) {
        unsigned x = __shfl_up(inc, dd, 64);
        if (lane >= dd) inc += x;
    }
    if (lane == 63) wsum[wid] = inc;
    __syncthreads();
    if (t == 0) {
        unsigned run = 0;
        for (int k = 0; k < 16; k++) { unsigned x = wsum[k]; wsum[k] = run; run += x; }
    }
    __syncthreads();
    unsigned ex = inc - v + wsum[wid];
    cur[t] = ex;
    if (t < nrows) startsKey[(unsigned)rel * N_ITEMS + (unsigned)row0 + t] = s0 + ex;
    __syncthreads();

    for (int i = t; i < n; i += 1024) {
        uint2 rc = recs[s0 + i];
        unsigned lrow = rc.x >> 17;
        unsigned pos = s0 + atomicAdd(&cur[lrow], 1u);
        recs2[pos] = make_uint2(rc.x & 0x1FFFFu, rc.y);
    }
}

// ---- P5: E -> bf16 copy (gather input only; residual stays fp32) ----
__global__ void tobf16_kernel(const float* __restrict__ E, unsigned short* __restrict__ Ebf) {
    int i = blockIdx.x * 256 + threadIdx.x;
    if (i < N_ITEMS * EMBED_DIM) {
        unsigned u = __float_as_uint(E[i]);
        unsigned r = (u + 0x7FFFu + ((u >> 16) & 1u)) >> 16;  // RNE
        Ebf[i] = (unsigned short)r;
    }
}

// ---- Phase B: CSR gather, 16 lanes x ushort4 per edge => 4 edges/wave-issue ----
// Register accumulation per sub-group; shfl_xor butterfly combine.
__launch_bounds__(192)
__global__ void gather_csr_kernel(const uint2* __restrict__ Ebf4,   // ushort4 rows viewed as uint2
                                  const float* __restrict__ E,
                                  const unsigned* __restrict__ starts,
                                  const uint2* __restrict__ recs,
                                  float* __restrict__ out) {
    __shared__ float part[N_REL * EMBED_DIM];
    int row = blockIdx.x;
    int w = threadIdx.x >> 6;      // relation 0..2
    int lane = threadIdx.x & 63;
    int sub = lane >> 4;           // edge stream 0..3
    int q = lane & 15;             // dim quad (4q .. 4q+3)

    unsigned key = (unsigned)w * N_ITEMS + (unsigned)row;
    unsigned s = starts[key];
    int n = (int)(starts[key + 1] - s);
    const uint2* __restrict__ p = recs + s;

    float a0 = 0.f, a1 = 0.f, a2 = 0.f, a3 = 0.f, deg = 0.f;

    int i = sub;
    for (; i + 12 < n; i += 16) {   // 4 edges/stream in flight (16 edges/wave)
        uint2 r0 = p[i], r1 = p[i + 4], r2 = p[i + 8], r3 = p[i + 12];
        uint2 e0 = Ebf4[r0.x * 16 + q];
        uint2 e1 = Ebf4[r1.x * 16 + q];
        uint2 e2 = Ebf4[r2.x * 16 + q];
        uint2 e3 = Ebf4[r3.x * 16 + q];
        float w0 = __uint_as_float(r0.y), w1 = __uint_as_float(r1.y);
        float w2 = __uint_as_float(r2.y), w3 = __uint_as_float(r3.y);
        a0 += w0 * __uint_as_float(e0.x << 16);
        a1 += w0 * __uint_as_float(e0.x & 0xFFFF0000u);
        a2 += w0 * __uint_as_float(e0.y << 16);
        a3 += w0 * __uint_as_float(e0.y & 0xFFFF0000u);
        deg += w0;
        a0 += w1 * __uint_as_float(e1.x << 16);
        a1 += w1 * __uint_as_float(e1.x & 0xFFFF0000u);
        a2 += w1 * __uint_as_float(e1.y << 16);
        a3 += w1 * __uint_as_float(e1.y & 0xFFFF0000u);
        deg += w1;
        a0 += w2 * __uint_as_float(e2.x << 16);
        a1 += w2 * __uint_as_float(e2.x & 0xFFFF0000u);
        a2 += w2 * __uint_as_float(e2.y << 16);
        a3 += w2 * __uint_as_float(e2.y & 0xFFFF0000u);
        deg += w2;
        a0 += w3 * __uint_as_float(e3.x << 16);
        a1 += w3 * __uint_as_float(e3.x & 0xFFFF0000u);
        a2 += w3 * __uint_as_float(e3.y << 16);
        a3 += w3 * __uint_as_float(e3.y & 0xFFFF0000u);
        deg += w3;
    }
    for (; i < n; i += 4) {
        uint2 r0 = p[i];
        uint2 e0 = Ebf4[r0.x * 16 + q];
        float w0 = __uint_as_float(r0.y);
        a0 += w0 * __uint_as_float(e0.x << 16);
        a1 += w0 * __uint_as_float(e0.x & 0xFFFF0000u);
        a2 += w0 * __uint_as_float(e0.y << 16);
        a3 += w0 * __uint_as_float(e0.y & 0xFFFF0000u);
        deg += w0;
    }

    // combine the 4 edge streams (lanes differing in bits 4,5)
    a0 += __shfl_xor(a0, 16, 64);  a0 += __shfl_xor(a0, 32, 64);
    a1 += __shfl_xor(a1, 16, 64);  a1 += __shfl_xor(a1, 32, 64);
    a2 += __shfl_xor(a2, 16, 64);  a2 += __shfl_xor(a2, 32, 64);
    a3 += __shfl_xor(a3, 16, 64);  a3 += __shfl_xor(a3, 32, 64);
    deg += __shfl_xor(deg, 16, 64); deg += __shfl_xor(deg, 32, 64);

    float inv = 1.0f / (3.0f * fmaxf(deg, 1.0f));
    if (sub == 0) {
        float4* p4 = (float4*)part;
        p4[w * 16 + q] = make_float4(a0 * inv, a1 * inv, a2 * inv, a3 * inv);
    }
    __syncthreads();
    if (threadIdx.x < EMBED_DIM) {
        int gi = row * EMBED_DIM + threadIdx.x;
        out[gi] = E[gi] + part[threadIdx.x]
                        + part[EMBED_DIM + threadIdx.x]
                        + part[2 * EMBED_DIM + threadIdx.x];
    }
}

// ============================ v5 fallback (R5 pipeline) ============================
#define NBS ((NKEY + 255) / 256)

__global__ void hist300_kernel(const int* __restrict__ rows, unsigned* __restrict__ cnt) {
    int stride = gridDim.x * blockDim.x;
    for (int i = blockIdx.x * blockDim.x + threadIdx.x; i < TOTAL_EDGES; i += stride) {
        unsigned r = (unsigned)i / (unsigned)N_EDGES;
        unsigned key = r * N_ITEMS + (unsigned)rows[i];
        atomicAdd(&cnt[key], 1u);
    }
}

__global__ void scan_blocksum(const unsigned* __restrict__ cnt, unsigned* __restrict__ bsum) {
    __shared__ unsigned s[256];
    int i = blockIdx.x * 256 + threadIdx.x;
    s[threadIdx.x] = (i < NKEY) ? cnt[i] : 0u;
    __syncthreads();
    for (int off = 128; off > 0; off >>= 1) {
        if (threadIdx.x < off) s[threadIdx.x] += s[threadIdx.x + off];
        __syncthreads();
    }
    if (threadIdx.x == 0) bsum[blockIdx.x] = s[0];
}

__global__ void scan_partials(unsigned* __restrict__ bsum, unsigned* __restrict__ starts) {
    const int IT = 5;
    int t = threadIdx.x;
    unsigned loc[IT];
    unsigned sum = 0;
    #pragma unroll
    for (int k = 0; k < IT; k++) {
        int idx = t * IT + k;
        loc[k] = (idx < NBS) ? bsum[idx] : 0u;
        sum += loc[k];
    }
    int lane = t & 63, wid = t >> 6;
    unsigned inc = sum;
    #pragma unroll
    for (int d = 1; d < 64; d <<= 1) {
        unsigned x = __shfl_up(inc, d, 64);
        if (lane >= d) inc += x;
    }
    __shared__ unsigned woff[4], woffEx[4];
    if (lane == 63) woff[wid] = inc;
    __syncthreads();
    if (t == 0) { unsigned run = 0; for (int k = 0; k < 4; k++) { woffEx[k] = run; run += woff[k]; } }
    __syncthreads();
    unsigned ex = inc - sum + woffEx[wid];
    #pragma unroll
    for (int k = 0; k < IT; k++) {
        int idx = t * IT + k;
        if (idx < NBS) { bsum[idx] = ex; ex += loc[k]; }
    }
    if (t == 0) starts[NKEY] = (unsigned)TOTAL_EDGES;
}

__global__ void scan_final(unsigned* key_arr,
                           const unsigned* __restrict__ bsum,
                           unsigned* __restrict__ cursor) {
    int i = blockIdx.x * 256 + threadIdx.x;
    unsigned v = (i < NKEY) ? key_arr[i] : 0u;
    int lane = threadIdx.x & 63, wid = threadIdx.x >> 6;
    unsigned inc = v;
    #pragma unroll
    for (int d = 1; d < 64; d <<= 1) {
        unsigned x = __shfl_up(inc, d, 64);
        if (lane >= d) inc += x;
    }
    __shared__ unsigned woff[4], woffEx[4];
    if (lane == 63) woff[wid] = inc;
    __syncthreads();
    if (threadIdx.x == 0) { unsigned run = 0; for (int k = 0; k < 4; k++) { woffEx[k] = run; run += woff[k]; } }
    __syncthreads();
    unsigned ex = inc - v + woffEx[wid] + bsum[blockIdx.x];
    if (i < NKEY) { key_arr[i] = ex; cursor[i] = ex; }
}

__global__ void binscatter2_kernel(const int* __restrict__ rows,
                                   const int* __restrict__ cols,
                                   const float* __restrict__ vals,
                                   unsigned* __restrict__ cursor,
                                   uint2* __restrict__ recs) {
    int stride = gridDim.x * blockDim.x;
    for (int i = blockIdx.x * blockDim.x + threadIdx.x; i < TOTAL_EDGES; i += stride) {
        unsigned r = (unsigned)i / (unsigned)N_EDGES;
        unsigned key = r * N_ITEMS + (unsigned)rows[i];
        unsigned pos = atomicAdd(&cursor[key], 1u);
        uint2 rec;
        rec.x = (unsigned)cols[i];
        rec.y = __float_as_uint(vals[i]);
        recs[pos] = rec;
    }
}

// fp32-E gather for the v5 fallback
__launch_bounds__(192)
__global__ void gather_csr_f32_kernel(const float* __restrict__ E,
                                      const unsigned* __restrict__ starts,
                                      const uint2* __restrict__ recs,
                                      float* __restrict__ out) {
    __shared__ float part[N_REL * EMBED_DIM];
    int row = blockIdx.x;
    int w = threadIdx.x >> 6;
    int d = threadIdx.x & 63;
    unsigned key = (unsigned)w * N_ITEMS + (unsigned)row;
    unsigned s = starts[key];
    int n = (int)(starts[key + 1] - s);
    const uint2* __restrict__ p = recs + s;
    float acc = 0.0f, deg = 0.0f;
    int j = 0;
    for (; j + 8 <= n; j += 8) {
        uint2 a[8];
        #pragma unroll
        for (int k = 0; k < 8; k++) a[k] = p[j + k];
        float e[8];
        #pragma unroll
        for (int k = 0; k < 8; k++) e[k] = E[a[k].x * EMBED_DIM + d];
        #pragma unroll
        for (int k = 0; k < 8; k++) {
            float wv = __uint_as_float(a[k].y);
            acc += wv * e[k];
            deg += wv;
        }
    }
    for (; j < n; j++) {
        uint2 a = p[j];
        float wv = __uint_as_float(a.y);
        acc += wv * E[a.x * EMBED_DIM + d];
        deg += wv;
    }
    part[w * EMBED_DIM + d] = acc / (3.0f * fmaxf(deg, 1.0f));
    __syncthreads();
    if (threadIdx.x < EMBED_DIM) {
        int gi = row * EMBED_DIM + threadIdx.x;
        out[gi] = E[gi] + part[threadIdx.x]
                        + part[EMBED_DIM + threadIdx.x]
                        + part[2 * EMBED_DIM + threadIdx.x];
    }
}

// ============================ R1 fallback ============================
__global__ void deg_kernel(const int* __restrict__ rows,
                           const float* __restrict__ vals,
                           float* __restrict__ deg) {
    long long i = (long long)blockIdx.x * blockDim.x + threadIdx.x;
    if (i >= TOTAL_EDGES) return;
    int r = (int)(i / N_EDGES);
    int row = rows[i];
    atomicAdd(&deg[(long long)r * N_ITEMS + row], vals[i]);
}

__global__ void inv_kernel(float* __restrict__ deg) {
    int i = blockIdx.x * blockDim.x + threadIdx.x;
    if (i >= N_REL * N_ITEMS) return;
    float d = deg[i];
    d = fmaxf(d, 1.0f);
    deg[i] = 1.0f / (3.0f * d);
}

__global__ void scatter_kernel(const float* __restrict__ E,
                               const int* __restrict__ rows,
                               const int* __restrict__ cols,
                               const float* __restrict__ vals,
                               const float* __restrict__ inv,
                               float* __restrict__ out) {
    long long t = (long long)blockIdx.x * blockDim.x + threadIdx.x;
    long long edge = t >> 6;
    int d = (int)(t & 63);
    if (edge >= TOTAL_EDGES) return;
    int r = (int)(edge / N_EDGES);
    int row = rows[edge];
    int col = cols[edge];
    float w = vals[edge] * inv[r * N_ITEMS + row];
    float msg = w * E[(long long)col * EMBED_DIM + d];
    atomicAdd(&out[(long long)row * EMBED_DIM + d], msg);
}

// ============================ launcher ============================
extern "C" void kernel_launch(void* const* d_in, const int* in_sizes, int n_in,
                              void* d_out, int out_size, void* d_ws, size_t ws_size,
                              hipStream_t stream) {
    const float* E    = (const float*)d_in[0];
    const int*   rows = (const int*)d_in[1];
    const int*   cols = (const int*)d_in[2];
    const float* vals = (const float*)d_in[3];
    float* out = (float*)d_out;

    // v8 workspace: startsKey[NKEY+1] | gcnt | gstart | gcursor | recs | recs2
    // Ebf (12.8 MB) reuses the recs buffer after bucket_sort no longer needs it.
    const size_t REGA = 1204224;                              // >= (NKEY+1)*4
    const size_t REGS = 4096;                                 // small arrays
    const size_t RECB = (size_t)TOTAL_EDGES * sizeof(uint2);  // 76.8 MB
    size_t need8 = REGA + 3 * REGS + 2 * RECB;

    const size_t REGC = 8192;
    size_t need5 = 2 * REGA + REGC + RECB;

    if (ws_size >= need8) {
        unsigned* startsKey = (unsigned*)d_ws;
        unsigned* gcnt      = (unsigned*)((char*)d_ws + REGA);
        unsigned* gstart    = (unsigned*)((char*)d_ws + REGA + REGS);
        unsigned* gcursor   = (unsigned*)((char*)d_ws + REGA + 2 * REGS);
        uint2*    recs      = (uint2*)((char*)d_ws + REGA + 3 * REGS);
        uint2*    recs2     = (uint2*)((char*)d_ws + REGA + 3 * REGS + RECB);
        unsigned short* Ebf = (unsigned short*)recs;  // reuse after bucket_sort

        hipMemsetAsync(gcnt, 0, NCB_TOT * sizeof(unsigned), stream);
        hist294_kernel<<<1172, 256, 0, stream>>>(rows, gcnt);
        scan294_kernel<<<1, 256, 0, stream>>>(gcnt, gstart, gcursor, startsKey);
        partition_kernel<<<(TOTAL_EDGES + TILE - 1) / TILE, 256, 0, stream>>>(
            rows, cols, vals, gcursor, recs);
        bucket_sort_kernel<<<NCB_TOT, 1024, 0, stream>>>(recs, gstart, startsKey, recs2);
        tobf16_kernel<<<(N_ITEMS * EMBED_DIM + 255) / 256, 256, 0, stream>>>(E, Ebf);
        gather_csr_kernel<<<N_ITEMS, 192, 0, stream>>>((const uint2*)Ebf, E, startsKey, recs2, out);
    } else if (ws_size >= need5) {
        unsigned* keyA   = (unsigned*)d_ws;
        unsigned* cursor = (unsigned*)((char*)d_ws + REGA);
        unsigned* bsum   = (unsigned*)((char*)d_ws + 2 * REGA);
        uint2*    recs   = (uint2*)((char*)d_ws + 2 * REGA + REGC);

        hipMemsetAsync(keyA, 0, NKEY * sizeof(unsigned), stream);
        hist300_kernel<<<1536, 256, 0, stream>>>(rows, keyA);
        scan_blocksum<<<NBS, 256, 0, stream>>>(keyA, bsum);
        scan_partials<<<1, 256, 0, stream>>>(bsum, keyA);
        scan_final<<<NBS, 256, 0, stream>>>(keyA, bsum, cursor);
        binscatter2_kernel<<<2048, 256, 0, stream>>>(rows, cols, vals, cursor, recs);
        gather_csr_f32_kernel<<<N_ITEMS, 192, 0, stream>>>(E, keyA, recs, out);
    } else {
        float* deg = (float*)d_ws;
        hipMemsetAsync(deg, 0, (size_t)N_REL * N_ITEMS * sizeof(float), stream);
        {
            long long total = TOTAL_EDGES;
            int block = 256;
            long long grid = (total + block - 1) / block;
            deg_kernel<<<(unsigned)grid, block, 0, stream>>>(rows, vals, deg);
        }
        {
            int total = N_REL * N_ITEMS;
            int block = 256;
            int grid = (total + block - 1) / block;
            inv_kernel<<<grid, block, 0, stream>>>(deg);
        }
        hipMemcpyAsync(out, E, (size_t)N_ITEMS * EMBED_DIM * sizeof(float),
                       hipMemcpyDeviceToDevice, stream);
        {
            long long threads = (long long)TOTAL_EDGES * 64;
            int block = 256;
            long long grid = (threads + block - 1) / block;
            scatter_kernel<<<(unsigned)grid, block, 0, stream>>>(E, rows, cols, vals, deg, out);
        }
    }
}